// Round 1
// baseline (384.054 us; speedup 1.0000x reference)
//
#include <hip/hip_runtime.h>
#include <hip/hip_bf16.h>
#include <math.h>

#define D_MODEL 512
#define N_HEADS 8
#define D_HEAD 64
#define D_FF 2048
#define SEQ 2048
#define BATCH 4
#define NTOK (BATCH * SEQ)

typedef __attribute__((ext_vector_type(8))) short short8;
typedef __attribute__((ext_vector_type(4))) float float4v;

static __device__ __forceinline__ unsigned short f2bf(float f) {
    union { float f; unsigned int i; } c; c.f = f;
    unsigned int i = c.i;
    unsigned int r = (i + 0x7FFFu + ((i >> 16) & 1u)) >> 16;   // round-nearest-even
    return (unsigned short)r;
}

// ---------------- weight convert + transpose: W[K][N] f32 -> Wt[N][K] bf16 ----------------
__global__ __launch_bounds__(256) void k_transpose_w(const float* __restrict__ W,
                                                     unsigned short* __restrict__ Wt,
                                                     int K, int N) {
    int id = blockIdx.x * 256 + threadIdx.x;
    if (id >= K * N) return;
    int k = id / N, n = id - k * N;
    Wt[(size_t)n * K + k] = f2bf(W[id]);
}

// ---------------- layernorm: one wave per 512-wide row, out bf16 ----------------
__global__ __launch_bounds__(256) void k_layernorm(const float* __restrict__ X,
                                                   const float* __restrict__ g,
                                                   const float* __restrict__ be,
                                                   unsigned short* __restrict__ Out) {
    int row  = blockIdx.x * 4 + (threadIdx.x >> 6);
    int lane = threadIdx.x & 63;
    const float* x = X + (size_t)row * D_MODEL + lane * 8;
    float4 v0 = ((const float4*)x)[0];
    float4 v1 = ((const float4*)x)[1];
    float vals[8] = {v0.x, v0.y, v0.z, v0.w, v1.x, v1.y, v1.z, v1.w};
    float s = 0.f, sq = 0.f;
#pragma unroll
    for (int j = 0; j < 8; j++) { s += vals[j]; sq += vals[j] * vals[j]; }
#pragma unroll
    for (int off = 32; off; off >>= 1) { s += __shfl_xor(s, off); sq += __shfl_xor(sq, off); }
    float mu  = s * (1.0f / D_MODEL);
    float var = sq * (1.0f / D_MODEL) - mu * mu;
    float inv = rsqrtf(var + 1e-5f);
    const float* gp  = g  + lane * 8;
    const float* bp  = be + lane * 8;
    float4 g0 = ((const float4*)gp)[0], g1v = ((const float4*)gp)[1];
    float4 b0 = ((const float4*)bp)[0], b1v = ((const float4*)bp)[1];
    float gs[8] = {g0.x, g0.y, g0.z, g0.w, g1v.x, g1v.y, g1v.z, g1v.w};
    float bs[8] = {b0.x, b0.y, b0.z, b0.w, b1v.x, b1v.y, b1v.z, b1v.w};
    unsigned short o[8];
#pragma unroll
    for (int j = 0; j < 8; j++) o[j] = f2bf((vals[j] - mu) * inv * gs[j] + bs[j]);
    unsigned short* op = Out + (size_t)row * D_MODEL + lane * 8;
    *(uint4*)op = *(uint4*)o;
}

// ---------------- generic 64x64-tile bf16 GEMM:  C = act(A @ Bt^T + bias) (+res) ----------
// A: [M][K] bf16 row-major ; Bt: [N][K] bf16 (i.e. B transposed)
// mode 0: bf16 out in head layout [b][h][s][dh]   (N must be 512)
// mode 1: bf16 out row-major, ReLU
// mode 2: f32 out row-major, + residual
__global__ __launch_bounds__(256) void k_gemm(const unsigned short* __restrict__ A,
                                              const unsigned short* __restrict__ Bt,
                                              const float* __restrict__ bias,
                                              const float* __restrict__ residual,
                                              void* __restrict__ Out,
                                              int M, int N, int K, int mode) {
    __shared__ unsigned short As[64][72];
    __shared__ unsigned short Bs[64][72];
    int m0 = blockIdx.x * 64, n0 = blockIdx.y * 64;
    int t = threadIdx.x;
    int w = t >> 6, l = t & 63, quad = l >> 4, lm = l & 15;
    int srow = t >> 2, sc8 = (t & 3) * 16;

    float4v acc[4];
#pragma unroll
    for (int i = 0; i < 4; i++) acc[i] = (float4v){0.f, 0.f, 0.f, 0.f};

    for (int k0 = 0; k0 < K; k0 += 64) {
        const unsigned short* ag = &A[(size_t)(m0 + srow) * K + k0 + sc8];
        const unsigned short* bg = &Bt[(size_t)(n0 + srow) * K + k0 + sc8];
        *(uint4*)&As[srow][sc8]     = *(const uint4*)ag;
        *(uint4*)&As[srow][sc8 + 8] = *(const uint4*)(ag + 8);
        *(uint4*)&Bs[srow][sc8]     = *(const uint4*)bg;
        *(uint4*)&Bs[srow][sc8 + 8] = *(const uint4*)(bg + 8);
        __syncthreads();
#pragma unroll
        for (int kc = 0; kc < 2; kc++) {
            short8 a = *(const short8*)&As[16 * w + lm][kc * 32 + quad * 8];
#pragma unroll
            for (int nn = 0; nn < 4; nn++) {
                short8 b = *(const short8*)&Bs[nn * 16 + lm][kc * 32 + quad * 8];
                acc[nn] = __builtin_amdgcn_mfma_f32_16x16x32_bf16(a, b, acc[nn], 0, 0, 0);
            }
        }
        __syncthreads();
    }

#pragma unroll
    for (int nn = 0; nn < 4; nn++) {
        int col = n0 + nn * 16 + lm;
        float bv = bias[col];
#pragma unroll
        for (int r = 0; r < 4; r++) {
            int mrow = m0 + 16 * w + quad * 4 + r;
            float v = acc[nn][r] + bv;
            if (mode == 1) v = fmaxf(v, 0.0f);
            if (mode == 2) {
                ((float*)Out)[(size_t)mrow * N + col] =
                    v + residual[(size_t)mrow * N + col];
            } else if (mode == 1) {
                ((unsigned short*)Out)[(size_t)mrow * N + col] = f2bf(v);
            } else {
                int b  = mrow >> 11, s = mrow & (SEQ - 1);
                int hh = col >> 6,   dh = col & 63;
                ((unsigned short*)Out)[(((size_t)(b * N_HEADS + hh) * SEQ) + s) * D_HEAD + dh] = f2bf(v);
            }
        }
    }
}

// ---------------- fused sigmoid attention: Y = X + sigmoid(QK^T/sqrt(D)) V --------------
// Q,K,V: [B*H][S][64] bf16 ; X,Y: [B][S][512] f32
__global__ __launch_bounds__(256) void k_attention(const unsigned short* __restrict__ Q,
                                                   const unsigned short* __restrict__ Kb,
                                                   const unsigned short* __restrict__ Vb,
                                                   const float* __restrict__ X,
                                                   float* __restrict__ Y) {
    __shared__ unsigned short Qs[64][72];
    __shared__ unsigned short Ks[64][72];
    __shared__ unsigned short Vt[64][72];
    __shared__ unsigned short Ps[64][72];
    int bh = blockIdx.y;
    int b = bh >> 3, h = bh & 7;
    size_t base = (size_t)bh * SEQ * D_HEAD;
    int s0 = blockIdx.x * 64;
    int t = threadIdx.x, w = t >> 6, l = t & 63, quad = l >> 4, lm = l & 15;
    int srow = t >> 2, sc8 = (t & 3) * 16;

    {
        const unsigned short* qg = &Q[base + (size_t)(s0 + srow) * D_HEAD + sc8];
        *(uint4*)&Qs[srow][sc8]     = *(const uint4*)qg;
        *(uint4*)&Qs[srow][sc8 + 8] = *(const uint4*)(qg + 8);
    }
    float4v acc[4];
#pragma unroll
    for (int i = 0; i < 4; i++) acc[i] = (float4v){0.f, 0.f, 0.f, 0.f};
    const float scale = 0.04419417382415922f;  // 1/sqrt(512)

    for (int tt = 0; tt < SEQ / 64; tt++) {
        size_t toff = base + (size_t)(tt * 64 + srow) * D_HEAD + sc8;
        const unsigned short* kg = &Kb[toff];
        *(uint4*)&Ks[srow][sc8]     = *(const uint4*)kg;
        *(uint4*)&Ks[srow][sc8 + 8] = *(const uint4*)(kg + 8);
        uint4 va = *(const uint4*)&Vb[toff];
        uint4 vb = *(const uint4*)(&Vb[toff] + 8);
        const unsigned short* vu = (const unsigned short*)&va;
#pragma unroll
        for (int j = 0; j < 8; j++) Vt[sc8 + j][srow] = vu[j];
        vu = (const unsigned short*)&vb;
#pragma unroll
        for (int j = 0; j < 8; j++) Vt[sc8 + 8 + j][srow] = vu[j];
        __syncthreads();

        float4v sc[4];
#pragma unroll
        for (int i = 0; i < 4; i++) sc[i] = (float4v){0.f, 0.f, 0.f, 0.f};
#pragma unroll
        for (int kc = 0; kc < 2; kc++) {
            short8 a = *(const short8*)&Qs[16 * w + lm][kc * 32 + quad * 8];
#pragma unroll
            for (int nn = 0; nn < 4; nn++) {
                short8 bf = *(const short8*)&Ks[nn * 16 + lm][kc * 32 + quad * 8];
                sc[nn] = __builtin_amdgcn_mfma_f32_16x16x32_bf16(a, bf, sc[nn], 0, 0, 0);
            }
        }
#pragma unroll
        for (int nn = 0; nn < 4; nn++) {
#pragma unroll
            for (int r = 0; r < 4; r++) {
                float pv = 1.0f / (1.0f + __expf(-sc[nn][r] * scale));
                Ps[16 * w + quad * 4 + r][nn * 16 + lm] = f2bf(pv);
            }
        }
        __syncthreads();
#pragma unroll
        for (int kc = 0; kc < 2; kc++) {
            short8 a = *(const short8*)&Ps[16 * w + lm][kc * 32 + quad * 8];
#pragma unroll
            for (int nn = 0; nn < 4; nn++) {
                short8 bf = *(const short8*)&Vt[nn * 16 + lm][kc * 32 + quad * 8];
                acc[nn] = __builtin_amdgcn_mfma_f32_16x16x32_bf16(a, bf, acc[nn], 0, 0, 0);
            }
        }
        __syncthreads();
    }

#pragma unroll
    for (int nn = 0; nn < 4; nn++) {
        int d = nn * 16 + lm;
#pragma unroll
        for (int r = 0; r < 4; r++) {
            int s = s0 + 16 * w + quad * 4 + r;
            size_t idx = ((size_t)(b * SEQ + s)) * D_MODEL + h * D_HEAD + d;
            Y[idx] = X[idx] + acc[nn][r];
        }
    }
}

extern "C" void kernel_launch(void* const* d_in, const int* in_sizes, int n_in,
                              void* d_out, int out_size, void* d_ws, size_t ws_size,
                              hipStream_t stream) {
    const float* x   = (const float*)d_in[0];
    const float* Wq  = (const float*)d_in[1];
    const float* bq  = (const float*)d_in[2];
    const float* Wk  = (const float*)d_in[3];
    const float* bk  = (const float*)d_in[4];
    const float* Wv  = (const float*)d_in[5];
    const float* bv  = (const float*)d_in[6];
    const float* W1  = (const float*)d_in[7];
    const float* b1  = (const float*)d_in[8];
    const float* W2  = (const float*)d_in[9];
    const float* b2  = (const float*)d_in[10];
    const float* g1  = (const float*)d_in[11];
    const float* be1 = (const float*)d_in[12];
    const float* g2  = (const float*)d_in[13];
    const float* be2 = (const float*)d_in[14];
    float* out = (float*)d_out;

    char* p = (char*)d_ws;
    unsigned short* xn  = (unsigned short*)p; p += (size_t)NTOK * D_MODEL * 2;
    unsigned short* yn  = (unsigned short*)p; p += (size_t)NTOK * D_MODEL * 2;
    float*          y   = (float*)p;          p += (size_t)NTOK * D_MODEL * 4;
    unsigned short* qb  = (unsigned short*)p; p += (size_t)NTOK * D_MODEL * 2;
    unsigned short* kb  = (unsigned short*)p; p += (size_t)NTOK * D_MODEL * 2;
    unsigned short* vb  = (unsigned short*)p; p += (size_t)NTOK * D_MODEL * 2;
    unsigned short* hb  = (unsigned short*)p; p += (size_t)NTOK * D_FF * 2;
    unsigned short* Wqt = (unsigned short*)p; p += (size_t)D_MODEL * D_MODEL * 2;
    unsigned short* Wkt = (unsigned short*)p; p += (size_t)D_MODEL * D_MODEL * 2;
    unsigned short* Wvt = (unsigned short*)p; p += (size_t)D_MODEL * D_MODEL * 2;
    unsigned short* W1t = (unsigned short*)p; p += (size_t)D_MODEL * D_FF * 2;
    unsigned short* W2t = (unsigned short*)p; p += (size_t)D_FF * D_MODEL * 2;

    // weights -> bf16 transposed [N][K]
    k_transpose_w<<<(D_MODEL * D_MODEL + 255) / 256, 256, 0, stream>>>(Wq, Wqt, D_MODEL, D_MODEL);
    k_transpose_w<<<(D_MODEL * D_MODEL + 255) / 256, 256, 0, stream>>>(Wk, Wkt, D_MODEL, D_MODEL);
    k_transpose_w<<<(D_MODEL * D_MODEL + 255) / 256, 256, 0, stream>>>(Wv, Wvt, D_MODEL, D_MODEL);
    k_transpose_w<<<(D_MODEL * D_FF + 255) / 256, 256, 0, stream>>>(W1, W1t, D_MODEL, D_FF);
    k_transpose_w<<<(D_FF * D_MODEL + 255) / 256, 256, 0, stream>>>(W2, W2t, D_FF, D_MODEL);

    // LN1
    k_layernorm<<<NTOK / 4, 256, 0, stream>>>(x, g1, be1, xn);

    // QKV projections -> head layout bf16
    dim3 gq(NTOK / 64, D_MODEL / 64);
    k_gemm<<<gq, 256, 0, stream>>>(xn, Wqt, bq, nullptr, qb, NTOK, D_MODEL, D_MODEL, 0);
    k_gemm<<<gq, 256, 0, stream>>>(xn, Wkt, bk, nullptr, kb, NTOK, D_MODEL, D_MODEL, 0);
    k_gemm<<<gq, 256, 0, stream>>>(xn, Wvt, bv, nullptr, vb, NTOK, D_MODEL, D_MODEL, 0);

    // attention + residual -> y
    dim3 ga(SEQ / 64, BATCH * N_HEADS);
    k_attention<<<ga, 256, 0, stream>>>(qb, kb, vb, x, y);

    // LN2
    k_layernorm<<<NTOK / 4, 256, 0, stream>>>(y, g2, be2, yn);

    // FFN
    dim3 g1d(NTOK / 64, D_FF / 64);
    k_gemm<<<g1d, 256, 0, stream>>>(yn, W1t, b1, nullptr, hb, NTOK, D_FF, D_MODEL, 1);
    dim3 g2d(NTOK / 64, D_MODEL / 64);
    k_gemm<<<g2d, 256, 0, stream>>>(hb, W2t, b2, y, out, NTOK, D_MODEL, D_FF, 2);
}

// Round 2
// 274.973 us; speedup vs baseline: 1.3967x; 1.3967x over previous
//
#include <hip/hip_runtime.h>
#include <hip/hip_bf16.h>
#include <math.h>

#define D_MODEL 512
#define N_HEADS 8
#define D_HEAD 64
#define D_FF 2048
#define SEQ 2048
#define BATCH 4
#define NTOK (BATCH * SEQ)
#define QSCALE 0.04419417382415922f   // 1/sqrt(512), folded into Q projection

typedef unsigned short ushort_t;
typedef __attribute__((ext_vector_type(8))) short short8;
typedef __attribute__((ext_vector_type(4))) float float4v;

static __device__ __forceinline__ ushort_t f2bf(float f) {
    union { float f; unsigned int i; } c; c.f = f;
    unsigned int i = c.i;
    unsigned int r = (i + 0x7FFFu + ((i >> 16) & 1u)) >> 16;   // RNE
    return (ushort_t)r;
}

static __device__ __forceinline__ unsigned int pack2bf(float a, float b) {
    union { __hip_bfloat162 h; unsigned int u; } c;
    c.h = __float22bfloat162_rn(make_float2(a, b));
    return c.u;
}

static __device__ __forceinline__ float sigmoid_f(float x) {
    return __builtin_amdgcn_rcpf(1.0f + __expf(-x));
}

// ---------------- weight convert + transpose: W[K][N] f32 -> Wt[N][K] bf16 ----------------
__global__ __launch_bounds__(256) void k_transpose_w(const float* __restrict__ W,
                                                     ushort_t* __restrict__ Wt,
                                                     int K, int N) {
    int id = blockIdx.x * 256 + threadIdx.x;
    if (id >= K * N) return;
    int k = id / N, n = id - k * N;
    Wt[(size_t)n * K + k] = f2bf(W[id]);
}

// ---------------- layernorm: one wave per 512-wide row, out bf16 ----------------
__global__ __launch_bounds__(256) void k_layernorm(const float* __restrict__ X,
                                                   const float* __restrict__ g,
                                                   const float* __restrict__ be,
                                                   ushort_t* __restrict__ Out) {
    int row  = blockIdx.x * 4 + (threadIdx.x >> 6);
    int lane = threadIdx.x & 63;
    const float* x = X + (size_t)row * D_MODEL + lane * 8;
    float4 v0 = ((const float4*)x)[0];
    float4 v1 = ((const float4*)x)[1];
    float vals[8] = {v0.x, v0.y, v0.z, v0.w, v1.x, v1.y, v1.z, v1.w};
    float s = 0.f, sq = 0.f;
#pragma unroll
    for (int j = 0; j < 8; j++) { s += vals[j]; sq += vals[j] * vals[j]; }
#pragma unroll
    for (int off = 32; off; off >>= 1) { s += __shfl_xor(s, off); sq += __shfl_xor(sq, off); }
    float mu  = s * (1.0f / D_MODEL);
    float var = sq * (1.0f / D_MODEL) - mu * mu;
    float inv = rsqrtf(var + 1e-5f);
    const float* gp  = g  + lane * 8;
    const float* bp  = be + lane * 8;
    float4 g0 = ((const float4*)gp)[0], g1v = ((const float4*)gp)[1];
    float4 b0 = ((const float4*)bp)[0], b1v = ((const float4*)bp)[1];
    float gs[8] = {g0.x, g0.y, g0.z, g0.w, g1v.x, g1v.y, g1v.z, g1v.w};
    float bs[8] = {b0.x, b0.y, b0.z, b0.w, b1v.x, b1v.y, b1v.z, b1v.w};
    ushort_t o[8];
#pragma unroll
    for (int j = 0; j < 8; j++) o[j] = f2bf((vals[j] - mu) * inv * gs[j] + bs[j]);
    ushort_t* op = Out + (size_t)row * D_MODEL + lane * 8;
    *(uint4*)op = *(uint4*)o;
}

// ---------------- 128x128-tile bf16 GEMM core: acc = A[M][K] @ Bt[N][K]^T -----------------
// BK=32, double-buffered LDS + register prefetch (1 barrier per K-iter).
__device__ __forceinline__ void gemm_core(const ushort_t* __restrict__ A,
                                          const ushort_t* __restrict__ Bt,
                                          int K, int m0, int n0,
                                          ushort_t (*As)[128][40], ushort_t (*Bs)[128][40],
                                          float4v acc[4][4]) {
    int t = threadIdx.x, w = t >> 6, l = t & 63, q = l >> 4, lm = l & 15;
    int mb = (w & 1) * 64, nb = (w >> 1) * 64;
    int srow = t >> 1, scol = (t & 1) * 16;
    const ushort_t* ag0 = A  + (size_t)(m0 + srow) * K + scol;
    const ushort_t* bg0 = Bt + (size_t)(n0 + srow) * K + scol;

    uint4 ar0 = *(const uint4*)(ag0),     ar1 = *(const uint4*)(ag0 + 8);
    uint4 br0 = *(const uint4*)(bg0),     br1 = *(const uint4*)(bg0 + 8);
    *(uint4*)&As[0][srow][scol] = ar0; *(uint4*)&As[0][srow][scol + 8] = ar1;
    *(uint4*)&Bs[0][srow][scol] = br0; *(uint4*)&Bs[0][srow][scol + 8] = br1;
    int T = K >> 5;
    ar0 = *(const uint4*)(ag0 + 32); ar1 = *(const uint4*)(ag0 + 40);
    br0 = *(const uint4*)(bg0 + 32); br1 = *(const uint4*)(bg0 + 40);
    __syncthreads();

    for (int kt = 0; kt < T; kt++) {
        int cur = kt & 1;
        short8 a[4], b[4];
#pragma unroll
        for (int i = 0; i < 4; i++) a[i] = *(const short8*)&As[cur][mb + 16 * i + lm][q * 8];
#pragma unroll
        for (int j = 0; j < 4; j++) b[j] = *(const short8*)&Bs[cur][nb + 16 * j + lm][q * 8];
#pragma unroll
        for (int i = 0; i < 4; i++)
#pragma unroll
            for (int j = 0; j < 4; j++)
                acc[i][j] = __builtin_amdgcn_mfma_f32_16x16x32_bf16(a[i], b[j], acc[i][j], 0, 0, 0);
        if (kt + 1 < T) {
            int nxt = 1 - cur;
            *(uint4*)&As[nxt][srow][scol] = ar0; *(uint4*)&As[nxt][srow][scol + 8] = ar1;
            *(uint4*)&Bs[nxt][srow][scol] = br0; *(uint4*)&Bs[nxt][srow][scol + 8] = br1;
            if (kt + 2 < T) {
                const ushort_t* ag = ag0 + (kt + 2) * 32;
                const ushort_t* bg = bg0 + (kt + 2) * 32;
                ar0 = *(const uint4*)(ag); ar1 = *(const uint4*)(ag + 8);
                br0 = *(const uint4*)(bg); br1 = *(const uint4*)(bg + 8);
            }
        }
        __syncthreads();
    }
}

// ---------------- fused QKV projection (N=1536): q,k head-layout; v transposed ------------
__global__ __launch_bounds__(256) void k_gemm_qkv(const ushort_t* __restrict__ A,
                                                  const ushort_t* __restrict__ Bt,
                                                  const float* __restrict__ bq,
                                                  const float* __restrict__ bk,
                                                  const float* __restrict__ bv,
                                                  ushort_t* __restrict__ qb,
                                                  ushort_t* __restrict__ kb,
                                                  ushort_t* __restrict__ vt) {
    __shared__ ushort_t As[2][128][40];
    __shared__ ushort_t Bs[2][128][40];
    int m0 = blockIdx.x * 128, n0 = blockIdx.y * 128;
    float4v acc[4][4];
#pragma unroll
    for (int i = 0; i < 4; i++)
#pragma unroll
        for (int j = 0; j < 4; j++) acc[i][j] = (float4v){0.f, 0.f, 0.f, 0.f};
    gemm_core(A, Bt, D_MODEL, m0, n0, As, Bs, acc);

    int t = threadIdx.x, w = t >> 6, l = t & 63, q = l >> 4, lm = l & 15;
    int mb = (w & 1) * 64, nb = (w >> 1) * 64;
    int mat = n0 >> 9, c0 = n0 & 511;     // 128-blocks never cross the 512 boundaries
    const float* bias = (mat == 0) ? bq : ((mat == 1) ? bk : bv);
#pragma unroll
    for (int j = 0; j < 4; j++) {
        int cl = c0 + nb + 16 * j + lm;
        int hh = cl >> 6, dh = cl & 63;
        float bvv = bias[cl];
#pragma unroll
        for (int i = 0; i < 4; i++) {
            int mr0 = m0 + mb + 16 * i + q * 4;
            int bb = mr0 >> 11, ss0 = mr0 & (SEQ - 1);
            if (mat == 2) {
                union { ushort_t s[4]; uint2 v; } pk;
#pragma unroll
                for (int r = 0; r < 4; r++) pk.s[r] = f2bf(acc[i][j][r] + bvv);
                *(uint2*)&vt[((size_t)(bb * N_HEADS + hh) * D_HEAD + dh) * SEQ + ss0] = pk.v;
            } else {
                ushort_t* dst = (mat == 0) ? qb : kb;
                float sc = (mat == 0) ? QSCALE : 1.0f;
#pragma unroll
                for (int r = 0; r < 4; r++)
                    dst[((size_t)(bb * N_HEADS + hh) * SEQ + ss0 + r) * D_HEAD + dh] =
                        f2bf((acc[i][j][r] + bvv) * sc);
            }
        }
    }
}

// ---------------- FFN1: relu(yn @ W1 + b1) -> bf16 row-major ------------------------------
__global__ __launch_bounds__(256) void k_gemm_ffn1(const ushort_t* __restrict__ A,
                                                   const ushort_t* __restrict__ Bt,
                                                   const float* __restrict__ b1,
                                                   ushort_t* __restrict__ hb) {
    __shared__ ushort_t As[2][128][40];
    __shared__ ushort_t Bs[2][128][40];
    int m0 = blockIdx.x * 128, n0 = blockIdx.y * 128;
    float4v acc[4][4];
#pragma unroll
    for (int i = 0; i < 4; i++)
#pragma unroll
        for (int j = 0; j < 4; j++) acc[i][j] = (float4v){0.f, 0.f, 0.f, 0.f};
    gemm_core(A, Bt, D_MODEL, m0, n0, As, Bs, acc);

    int t = threadIdx.x, w = t >> 6, l = t & 63, q = l >> 4, lm = l & 15;
    int mb = (w & 1) * 64, nb = (w >> 1) * 64;
#pragma unroll
    for (int j = 0; j < 4; j++) {
        int cl = n0 + nb + 16 * j + lm;
        float bvv = b1[cl];
#pragma unroll
        for (int i = 0; i < 4; i++) {
            int mr0 = m0 + mb + 16 * i + q * 4;
#pragma unroll
            for (int r = 0; r < 4; r++)
                hb[(size_t)(mr0 + r) * D_FF + cl] = f2bf(fmaxf(acc[i][j][r] + bvv, 0.f));
        }
    }
}

// ---------------- FFN2: hb @ W2 + b2 + residual -> f32 out --------------------------------
__global__ __launch_bounds__(256) void k_gemm_ffn2(const ushort_t* __restrict__ A,
                                                   const ushort_t* __restrict__ Bt,
                                                   const float* __restrict__ b2,
                                                   const float* __restrict__ res,
                                                   float* __restrict__ out) {
    __shared__ ushort_t As[2][128][40];
    __shared__ ushort_t Bs[2][128][40];
    int m0 = blockIdx.x * 128, n0 = blockIdx.y * 128;
    float4v acc[4][4];
#pragma unroll
    for (int i = 0; i < 4; i++)
#pragma unroll
        for (int j = 0; j < 4; j++) acc[i][j] = (float4v){0.f, 0.f, 0.f, 0.f};
    gemm_core(A, Bt, D_FF, m0, n0, As, Bs, acc);

    int t = threadIdx.x, w = t >> 6, l = t & 63, q = l >> 4, lm = l & 15;
    int mb = (w & 1) * 64, nb = (w >> 1) * 64;
#pragma unroll
    for (int j = 0; j < 4; j++) {
        int cl = n0 + nb + 16 * j + lm;
        float bvv = b2[cl];
#pragma unroll
        for (int i = 0; i < 4; i++) {
            int mr0 = m0 + mb + 16 * i + q * 4;
#pragma unroll
            for (int r = 0; r < 4; r++) {
                size_t idx = (size_t)(mr0 + r) * D_MODEL + cl;
                out[idx] = acc[i][j][r] + bvv + res[idx];
            }
        }
    }
}

// ---------------- fused sigmoid attention: Y = X + sigmoid(QK^T/sqrt(D)) V ----------------
// Q,K: [BH][S][64] bf16 (Q pre-scaled); Vt: [BH][64][S] bf16; X,Y: [B][S][512] f32
// S^T trick: MFMA(A=K, B=Q) -> lane holds 4 contiguous-t scores per column -> b64 P stores.
// Q frags in registers; K/V double-buffered in LDS with register prefetch (1 barrier/iter).
__global__ __launch_bounds__(256) void k_attention(const ushort_t* __restrict__ Q,
                                                   const ushort_t* __restrict__ Kb,
                                                   const ushort_t* __restrict__ Vt,
                                                   const float* __restrict__ X,
                                                   float* __restrict__ Y) {
    __shared__ ushort_t Ks[2][64][72];
    __shared__ ushort_t Vs[2][64][72];
    __shared__ ushort_t Ps[128][72];
    int bh = blockIdx.y;
    int b = bh >> 3, h = bh & 7;
    size_t base = (size_t)bh * SEQ * D_HEAD;   // same extent for K and Vt
    int s0 = blockIdx.x * 128;
    int t = threadIdx.x, w = t >> 6, l = t & 63, q = l >> 4, lm = l & 15;
    int srow = t >> 2, sc = (t & 3) * 16;

    // Q fragments in registers (reused for all 32 K/V tiles)
    short8 qf[2][2];
#pragma unroll
    for (int nt = 0; nt < 2; nt++)
#pragma unroll
        for (int kc = 0; kc < 2; kc++) {
            const ushort_t* qg = Q + base + (size_t)(s0 + 32 * w + 16 * nt + lm) * D_HEAD + kc * 32 + q * 8;
            uint4 u = *(const uint4*)qg;
            qf[nt][kc] = *(const short8*)&u;
        }

    float4v o[2][4];
#pragma unroll
    for (int nt = 0; nt < 2; nt++)
#pragma unroll
        for (int dj = 0; dj < 4; dj++) o[nt][dj] = (float4v){0.f, 0.f, 0.f, 0.f};

    uint4 kr0, kr1, vr0, vr1;
    const ushort_t* kg0 = Kb + base + (size_t)srow * D_HEAD + sc;   // + tt*64*D_HEAD
    const ushort_t* vg0 = Vt + base + (size_t)srow * SEQ + sc;      // + tt*64

    // prologue: tile 0 regs -> LDS buf0 ; tile 1 -> regs
    kr0 = *(const uint4*)(kg0); kr1 = *(const uint4*)(kg0 + 8);
    vr0 = *(const uint4*)(vg0); vr1 = *(const uint4*)(vg0 + 8);
    *(uint4*)&Ks[0][srow][sc] = kr0; *(uint4*)&Ks[0][srow][sc + 8] = kr1;
    *(uint4*)&Vs[0][srow][sc] = vr0; *(uint4*)&Vs[0][srow][sc + 8] = vr1;
    kr0 = *(const uint4*)(kg0 + 64 * D_HEAD); kr1 = *(const uint4*)(kg0 + 64 * D_HEAD + 8);
    vr0 = *(const uint4*)(vg0 + 64);          vr1 = *(const uint4*)(vg0 + 64 + 8);
    __syncthreads();

    for (int tt = 0; tt < SEQ / 64; tt++) {
        int cur = tt & 1;
        // --- S^T = K Q^T : lane holds S[s=32w+16nt+lm][t=16mt+4q+r] ---
        float4v st[4][2];
#pragma unroll
        for (int mt = 0; mt < 4; mt++)
#pragma unroll
            for (int nt = 0; nt < 2; nt++) st[mt][nt] = (float4v){0.f, 0.f, 0.f, 0.f};
#pragma unroll
        for (int kc = 0; kc < 2; kc++) {
            short8 a[4];
#pragma unroll
            for (int mt = 0; mt < 4; mt++) a[mt] = *(const short8*)&Ks[cur][16 * mt + lm][kc * 32 + q * 8];
#pragma unroll
            for (int mt = 0; mt < 4; mt++)
#pragma unroll
                for (int nt = 0; nt < 2; nt++)
                    st[mt][nt] = __builtin_amdgcn_mfma_f32_16x16x32_bf16(a[mt], qf[nt][kc], st[mt][nt], 0, 0, 0);
        }
        // --- sigmoid + P store (b64, contiguous t; intra-wave, no barrier needed) ---
#pragma unroll
        for (int mt = 0; mt < 4; mt++)
#pragma unroll
            for (int nt = 0; nt < 2; nt++) {
                float4v s4 = st[mt][nt];
                uint2 pk;
                pk.x = pack2bf(sigmoid_f(s4[0]), sigmoid_f(s4[1]));
                pk.y = pack2bf(sigmoid_f(s4[2]), sigmoid_f(s4[3]));
                *(uint2*)&Ps[32 * w + 16 * nt + lm][16 * mt + 4 * q] = pk;
            }
        // --- O += P V  (A=P rows s, B=Vs rows d) ---
#pragma unroll
        for (int kc = 0; kc < 2; kc++) {
            short8 ap[2], bv[4];
#pragma unroll
            for (int nt = 0; nt < 2; nt++) ap[nt] = *(const short8*)&Ps[32 * w + 16 * nt + lm][kc * 32 + q * 8];
#pragma unroll
            for (int dj = 0; dj < 4; dj++) bv[dj] = *(const short8*)&Vs[cur][16 * dj + lm][kc * 32 + q * 8];
#pragma unroll
            for (int nt = 0; nt < 2; nt++)
#pragma unroll
                for (int dj = 0; dj < 4; dj++)
                    o[nt][dj] = __builtin_amdgcn_mfma_f32_16x16x32_bf16(ap[nt], bv[dj], o[nt][dj], 0, 0, 0);
        }
        // --- pipeline: regs -> other buf; issue loads for tt+2 ---
        if (tt + 1 < SEQ / 64) {
            int nxt = 1 - cur;
            *(uint4*)&Ks[nxt][srow][sc] = kr0; *(uint4*)&Ks[nxt][srow][sc + 8] = kr1;
            *(uint4*)&Vs[nxt][srow][sc] = vr0; *(uint4*)&Vs[nxt][srow][sc + 8] = vr1;
            if (tt + 2 < SEQ / 64) {
                const ushort_t* kg = kg0 + (size_t)(tt + 2) * 64 * D_HEAD;
                const ushort_t* vg = vg0 + (tt + 2) * 64;
                kr0 = *(const uint4*)(kg); kr1 = *(const uint4*)(kg + 8);
                vr0 = *(const uint4*)(vg); vr1 = *(const uint4*)(vg + 8);
            }
        }
        __syncthreads();
    }

    // epilogue: Y = X + O
#pragma unroll
    for (int nt = 0; nt < 2; nt++)
#pragma unroll
        for (int dj = 0; dj < 4; dj++) {
            int d = 16 * dj + lm;
#pragma unroll
            for (int r = 0; r < 4; r++) {
                int s = s0 + 32 * w + 16 * nt + q * 4 + r;
                size_t idx = ((size_t)(b * SEQ + s)) * D_MODEL + h * D_HEAD + d;
                Y[idx] = X[idx] + o[nt][dj][r];
            }
        }
}

extern "C" void kernel_launch(void* const* d_in, const int* in_sizes, int n_in,
                              void* d_out, int out_size, void* d_ws, size_t ws_size,
                              hipStream_t stream) {
    const float* x   = (const float*)d_in[0];
    const float* Wq  = (const float*)d_in[1];
    const float* bq  = (const float*)d_in[2];
    const float* Wk  = (const float*)d_in[3];
    const float* bk  = (const float*)d_in[4];
    const float* Wv  = (const float*)d_in[5];
    const float* bv  = (const float*)d_in[6];
    const float* W1  = (const float*)d_in[7];
    const float* b1  = (const float*)d_in[8];
    const float* W2  = (const float*)d_in[9];
    const float* b2  = (const float*)d_in[10];
    const float* g1  = (const float*)d_in[11];
    const float* be1 = (const float*)d_in[12];
    const float* g2  = (const float*)d_in[13];
    const float* be2 = (const float*)d_in[14];
    float* out = (float*)d_out;

    char* p = (char*)d_ws;
    ushort_t* xn    = (ushort_t*)p; p += (size_t)NTOK * D_MODEL * 2;
    ushort_t* yn    = (ushort_t*)p; p += (size_t)NTOK * D_MODEL * 2;
    float*    y     = (float*)p;    p += (size_t)NTOK * D_MODEL * 4;
    ushort_t* qb    = (ushort_t*)p; p += (size_t)NTOK * D_MODEL * 2;
    ushort_t* kb    = (ushort_t*)p; p += (size_t)NTOK * D_MODEL * 2;
    ushort_t* vt    = (ushort_t*)p; p += (size_t)NTOK * D_MODEL * 2;
    ushort_t* hb    = (ushort_t*)p; p += (size_t)NTOK * D_FF * 2;
    ushort_t* Wqkvt = (ushort_t*)p; p += (size_t)3 * D_MODEL * D_MODEL * 2;
    ushort_t* W1t   = (ushort_t*)p; p += (size_t)D_MODEL * D_FF * 2;
    ushort_t* W2t   = (ushort_t*)p; p += (size_t)D_FF * D_MODEL * 2;

    // weights -> bf16 transposed [N][K]; q,k,v concatenated along N
    k_transpose_w<<<(D_MODEL * D_MODEL + 255) / 256, 256, 0, stream>>>(Wq, Wqkvt, D_MODEL, D_MODEL);
    k_transpose_w<<<(D_MODEL * D_MODEL + 255) / 256, 256, 0, stream>>>(Wk, Wqkvt + (size_t)D_MODEL * D_MODEL, D_MODEL, D_MODEL);
    k_transpose_w<<<(D_MODEL * D_MODEL + 255) / 256, 256, 0, stream>>>(Wv, Wqkvt + (size_t)2 * D_MODEL * D_MODEL, D_MODEL, D_MODEL);
    k_transpose_w<<<(D_MODEL * D_FF + 255) / 256, 256, 0, stream>>>(W1, W1t, D_MODEL, D_FF);
    k_transpose_w<<<(D_FF * D_MODEL + 255) / 256, 256, 0, stream>>>(W2, W2t, D_FF, D_MODEL);

    // LN1
    k_layernorm<<<NTOK / 4, 256, 0, stream>>>(x, g1, be1, xn);

    // fused QKV projection (N=1536)
    dim3 gq(NTOK / 128, (3 * D_MODEL) / 128);
    k_gemm_qkv<<<gq, 256, 0, stream>>>(xn, Wqkvt, bq, bk, bv, qb, kb, vt);

    // attention + residual -> y
    dim3 ga(SEQ / 128, BATCH * N_HEADS);
    k_attention<<<ga, 256, 0, stream>>>(qb, kb, vt, x, y);

    // LN2
    k_layernorm<<<NTOK / 4, 256, 0, stream>>>(y, g2, be2, yn);

    // FFN
    dim3 g1d(NTOK / 128, D_FF / 128);
    k_gemm_ffn1<<<g1d, 256, 0, stream>>>(yn, W1t, b1, hb);
    dim3 g2d(NTOK / 128, D_MODEL / 128);
    k_gemm_ffn2<<<g2d, 256, 0, stream>>>(hb, W2t, b2, y, out);
}

// Round 3
// 274.804 us; speedup vs baseline: 1.3976x; 1.0006x over previous
//
#include <hip/hip_runtime.h>
#include <hip/hip_bf16.h>
#include <math.h>

#define D_MODEL 512
#define N_HEADS 8
#define D_HEAD 64
#define D_FF 2048
#define SEQ 2048
#define BATCH 4
#define NTOK (BATCH * SEQ)
#define QSCALE 0.04419417382415922f   // 1/sqrt(512), folded into Q projection

typedef unsigned short ushort_t;
typedef __attribute__((ext_vector_type(8))) short short8;
typedef __attribute__((ext_vector_type(4))) short short4v;
typedef __attribute__((ext_vector_type(4))) float float4v;

static __device__ __forceinline__ ushort_t f2bf(float f) {
    union { float f; unsigned int i; } c; c.f = f;
    unsigned int i = c.i;
    unsigned int r = (i + 0x7FFFu + ((i >> 16) & 1u)) >> 16;   // RNE
    return (ushort_t)r;
}

static __device__ __forceinline__ unsigned int pack2bf(float a, float b) {
    union { __hip_bfloat162 h; unsigned int u; } c;
    c.h = __float22bfloat162_rn(make_float2(a, b));
    return c.u;
}

static __device__ __forceinline__ float sigmoid_f(float x) {
    return __builtin_amdgcn_rcpf(1.0f + __expf(-x));
}

// ------------- all weights -> bf16 transposed [N][K], one kernel -------------------------
// Wqkvt: 3 x [512][512]; W1t: [2048][512]; W2t: [512][2048]
__global__ __launch_bounds__(256) void k_prep_weights(const float* __restrict__ Wq,
                                                      const float* __restrict__ Wk,
                                                      const float* __restrict__ Wv,
                                                      const float* __restrict__ W1,
                                                      const float* __restrict__ W2,
                                                      ushort_t* __restrict__ Wqkvt,
                                                      ushort_t* __restrict__ W1t,
                                                      ushort_t* __restrict__ W2t) {
    int id = blockIdx.x * 256 + threadIdx.x;
    if (id < 3 * 262144) {
        int m = id >> 18, r = id & 262143;
        int k = r >> 9, n = r & 511;
        const float* src = (m == 0) ? Wq : ((m == 1) ? Wk : Wv);
        Wqkvt[((size_t)m * 512 + n) * 512 + k] = f2bf(src[r]);
        return;
    }
    int id2 = id - 3 * 262144;
    if (id2 < 1048576) {                 // W1 [512][2048] -> [2048][512]
        int k = id2 >> 11, n = id2 & 2047;
        W1t[(size_t)n * 512 + k] = f2bf(W1[id2]);
        return;
    }
    int id3 = id2 - 1048576;
    if (id3 < 1048576) {                 // W2 [2048][512] -> [512][2048]
        int k = id3 >> 9, n = id3 & 511;
        W2t[(size_t)n * 2048 + k] = f2bf(W2[id3]);
    }
}

// ---------------- layernorm: one wave per 512-wide row, out bf16 ----------------
__global__ __launch_bounds__(256) void k_layernorm(const float* __restrict__ X,
                                                   const float* __restrict__ g,
                                                   const float* __restrict__ be,
                                                   ushort_t* __restrict__ Out) {
    int row  = blockIdx.x * 4 + (threadIdx.x >> 6);
    int lane = threadIdx.x & 63;
    const float* x = X + (size_t)row * D_MODEL + lane * 8;
    float4 v0 = ((const float4*)x)[0];
    float4 v1 = ((const float4*)x)[1];
    float vals[8] = {v0.x, v0.y, v0.z, v0.w, v1.x, v1.y, v1.z, v1.w};
    float s = 0.f, sq = 0.f;
#pragma unroll
    for (int j = 0; j < 8; j++) { s += vals[j]; sq += vals[j] * vals[j]; }
#pragma unroll
    for (int off = 32; off; off >>= 1) { s += __shfl_xor(s, off); sq += __shfl_xor(sq, off); }
    float mu  = s * (1.0f / D_MODEL);
    float var = sq * (1.0f / D_MODEL) - mu * mu;
    float inv = rsqrtf(var + 1e-5f);
    const float* gp  = g  + lane * 8;
    const float* bp  = be + lane * 8;
    float4 g0 = ((const float4*)gp)[0], g1v = ((const float4*)gp)[1];
    float4 b0 = ((const float4*)bp)[0], b1v = ((const float4*)bp)[1];
    float gs[8] = {g0.x, g0.y, g0.z, g0.w, g1v.x, g1v.y, g1v.z, g1v.w};
    float bs[8] = {b0.x, b0.y, b0.z, b0.w, b1v.x, b1v.y, b1v.z, b1v.w};
    ushort_t o[8];
#pragma unroll
    for (int j = 0; j < 8; j++) o[j] = f2bf((vals[j] - mu) * inv * gs[j] + bs[j]);
    ushort_t* op = Out + (size_t)row * D_MODEL + lane * 8;
    *(uint4*)op = *(uint4*)o;
}

// ---------------- 128x128-tile bf16 GEMM core: acc = A[M][K] @ Bt[N][K]^T -----------------
// BK=32, double-buffered LDS + register prefetch (1 barrier per K-iter).
__device__ __forceinline__ void gemm_core(const ushort_t* __restrict__ A,
                                          const ushort_t* __restrict__ Bt,
                                          int K, int m0, int n0,
                                          ushort_t (*As)[128][40], ushort_t (*Bs)[128][40],
                                          float4v acc[4][4]) {
    int t = threadIdx.x, w = t >> 6, l = t & 63, q = l >> 4, lm = l & 15;
    int mb = (w & 1) * 64, nb = (w >> 1) * 64;
    int srow = t >> 1, scol = (t & 1) * 16;
    const ushort_t* ag0 = A  + (size_t)(m0 + srow) * K + scol;
    const ushort_t* bg0 = Bt + (size_t)(n0 + srow) * K + scol;

    uint4 ar0 = *(const uint4*)(ag0),     ar1 = *(const uint4*)(ag0 + 8);
    uint4 br0 = *(const uint4*)(bg0),     br1 = *(const uint4*)(bg0 + 8);
    *(uint4*)&As[0][srow][scol] = ar0; *(uint4*)&As[0][srow][scol + 8] = ar1;
    *(uint4*)&Bs[0][srow][scol] = br0; *(uint4*)&Bs[0][srow][scol + 8] = br1;
    int T = K >> 5;
    ar0 = *(const uint4*)(ag0 + 32); ar1 = *(const uint4*)(ag0 + 40);
    br0 = *(const uint4*)(bg0 + 32); br1 = *(const uint4*)(bg0 + 40);
    __syncthreads();

    for (int kt = 0; kt < T; kt++) {
        int cur = kt & 1;
        short8 a[4], b[4];
#pragma unroll
        for (int i = 0; i < 4; i++) a[i] = *(const short8*)&As[cur][mb + 16 * i + lm][q * 8];
#pragma unroll
        for (int j = 0; j < 4; j++) b[j] = *(const short8*)&Bs[cur][nb + 16 * j + lm][q * 8];
#pragma unroll
        for (int i = 0; i < 4; i++)
#pragma unroll
            for (int j = 0; j < 4; j++)
                acc[i][j] = __builtin_amdgcn_mfma_f32_16x16x32_bf16(a[i], b[j], acc[i][j], 0, 0, 0);
        if (kt + 1 < T) {
            int nxt = 1 - cur;
            *(uint4*)&As[nxt][srow][scol] = ar0; *(uint4*)&As[nxt][srow][scol + 8] = ar1;
            *(uint4*)&Bs[nxt][srow][scol] = br0; *(uint4*)&Bs[nxt][srow][scol + 8] = br1;
            if (kt + 2 < T) {
                const ushort_t* ag = ag0 + (kt + 2) * 32;
                const ushort_t* bg = bg0 + (kt + 2) * 32;
                ar0 = *(const uint4*)(ag); ar1 = *(const uint4*)(ag + 8);
                br0 = *(const uint4*)(bg); br1 = *(const uint4*)(bg + 8);
            }
        }
        __syncthreads();
    }
}

// ---------------- fused QKV projection (N=1536): q,k head-layout; v transposed ------------
__global__ __launch_bounds__(256) void k_gemm_qkv(const ushort_t* __restrict__ A,
                                                  const ushort_t* __restrict__ Bt,
                                                  const float* __restrict__ bq,
                                                  const float* __restrict__ bk,
                                                  const float* __restrict__ bv,
                                                  ushort_t* __restrict__ qb,
                                                  ushort_t* __restrict__ kb,
                                                  ushort_t* __restrict__ vt) {
    __shared__ ushort_t As[2][128][40];
    __shared__ ushort_t Bs[2][128][40];
    int m0 = blockIdx.x * 128, n0 = blockIdx.y * 128;
    float4v acc[4][4];
#pragma unroll
    for (int i = 0; i < 4; i++)
#pragma unroll
        for (int j = 0; j < 4; j++) acc[i][j] = (float4v){0.f, 0.f, 0.f, 0.f};
    gemm_core(A, Bt, D_MODEL, m0, n0, As, Bs, acc);

    int t = threadIdx.x, w = t >> 6, l = t & 63, q = l >> 4, lm = l & 15;
    int mb = (w & 1) * 64, nb = (w >> 1) * 64;
    int mat = n0 >> 9, c0 = n0 & 511;     // 128-blocks never cross the 512 boundaries
    const float* bias = (mat == 0) ? bq : ((mat == 1) ? bk : bv);
#pragma unroll
    for (int j = 0; j < 4; j++) {
        int cl = c0 + nb + 16 * j + lm;
        int hh = cl >> 6, dh = cl & 63;
        float bvv = bias[cl];
#pragma unroll
        for (int i = 0; i < 4; i++) {
            int mr0 = m0 + mb + 16 * i + q * 4;
            int bb = mr0 >> 11, ss0 = mr0 & (SEQ - 1);
            if (mat == 2) {
                union { ushort_t s[4]; uint2 v; } pk;
#pragma unroll
                for (int r = 0; r < 4; r++) pk.s[r] = f2bf(acc[i][j][r] + bvv);
                *(uint2*)&vt[((size_t)(bb * N_HEADS + hh) * D_HEAD + dh) * SEQ + ss0] = pk.v;
            } else {
                ushort_t* dst = (mat == 0) ? qb : kb;
                float sc = (mat == 0) ? QSCALE : 1.0f;
#pragma unroll
                for (int r = 0; r < 4; r++)
                    dst[((size_t)(bb * N_HEADS + hh) * SEQ + ss0 + r) * D_HEAD + dh] =
                        f2bf((acc[i][j][r] + bvv) * sc);
            }
        }
    }
}

// ---------------- FFN1: relu(yn @ W1 + b1) -> bf16 row-major ------------------------------
__global__ __launch_bounds__(256) void k_gemm_ffn1(const ushort_t* __restrict__ A,
                                                   const ushort_t* __restrict__ Bt,
                                                   const float* __restrict__ b1,
                                                   ushort_t* __restrict__ hb) {
    __shared__ ushort_t As[2][128][40];
    __shared__ ushort_t Bs[2][128][40];
    int m0 = blockIdx.x * 128, n0 = blockIdx.y * 128;
    float4v acc[4][4];
#pragma unroll
    for (int i = 0; i < 4; i++)
#pragma unroll
        for (int j = 0; j < 4; j++) acc[i][j] = (float4v){0.f, 0.f, 0.f, 0.f};
    gemm_core(A, Bt, D_MODEL, m0, n0, As, Bs, acc);

    int t = threadIdx.x, w = t >> 6, l = t & 63, q = l >> 4, lm = l & 15;
    int mb = (w & 1) * 64, nb = (w >> 1) * 64;
#pragma unroll
    for (int j = 0; j < 4; j++) {
        int cl = n0 + nb + 16 * j + lm;
        float bvv = b1[cl];
#pragma unroll
        for (int i = 0; i < 4; i++) {
            int mr0 = m0 + mb + 16 * i + q * 4;
#pragma unroll
            for (int r = 0; r < 4; r++)
                hb[(size_t)(mr0 + r) * D_FF + cl] = f2bf(fmaxf(acc[i][j][r] + bvv, 0.f));
        }
    }
}

// ---------------- FFN2: hb @ W2 + b2 + residual -> f32 out --------------------------------
__global__ __launch_bounds__(256) void k_gemm_ffn2(const ushort_t* __restrict__ A,
                                                   const ushort_t* __restrict__ Bt,
                                                   const float* __restrict__ b2,
                                                   const float* __restrict__ res,
                                                   float* __restrict__ out) {
    __shared__ ushort_t As[2][128][40];
    __shared__ ushort_t Bs[2][128][40];
    int m0 = blockIdx.x * 128, n0 = blockIdx.y * 128;
    float4v acc[4][4];
#pragma unroll
    for (int i = 0; i < 4; i++)
#pragma unroll
        for (int j = 0; j < 4; j++) acc[i][j] = (float4v){0.f, 0.f, 0.f, 0.f};
    gemm_core(A, Bt, D_FF, m0, n0, As, Bs, acc);

    int t = threadIdx.x, w = t >> 6, l = t & 63, q = l >> 4, lm = l & 15;
    int mb = (w & 1) * 64, nb = (w >> 1) * 64;
#pragma unroll
    for (int j = 0; j < 4; j++) {
        int cl = n0 + nb + 16 * j + lm;
        float bvv = b2[cl];
#pragma unroll
        for (int i = 0; i < 4; i++) {
            int mr0 = m0 + mb + 16 * i + q * 4;
#pragma unroll
            for (int r = 0; r < 4; r++) {
                size_t idx = (size_t)(mr0 + r) * D_MODEL + cl;
                out[idx] = acc[i][j][r] + bvv + res[idx];
            }
        }
    }
}

// ---------------- fused sigmoid attention: Y = X + sigmoid(QK^T/sqrt(D)) V ----------------
// Q,K: [BH][S][64] bf16 (Q pre-scaled); Vt: [BH][64][S] bf16; X,Y: [B][S][512] f32
// S^T = K Q^T (C-layout: s=lane&15, t=quad*4+r) -> sigma -> packed bf16 pairs are DIRECTLY
// valid 16x16x16 MFMA fragments (A/B layout: row=lane&15, k=quad*4+j). PV computed as
// O^T = MFMA(A=V^T-frag, B=P-frag) with K=16 -> NO P LDS round-trip at all.
__global__ __launch_bounds__(256) void k_attention(const ushort_t* __restrict__ Q,
                                                   const ushort_t* __restrict__ Kb,
                                                   const ushort_t* __restrict__ Vt,
                                                   const float* __restrict__ X,
                                                   float* __restrict__ Y) {
    __shared__ ushort_t Ks[2][64][72];
    __shared__ ushort_t Vs[2][64][72];
    int bh = blockIdx.y;
    int b = bh >> 3, h = bh & 7;
    size_t base = (size_t)bh * SEQ * D_HEAD;   // same extent for K and Vt
    int s0 = blockIdx.x * 128;
    int t = threadIdx.x, w = t >> 6, l = t & 63, q = l >> 4, lm = l & 15;
    int srow = t >> 2, sc = (t & 3) * 16;

    // Q fragments in registers (reused for all 32 K/V tiles)
    short8 qf[2][2];
#pragma unroll
    for (int nt = 0; nt < 2; nt++)
#pragma unroll
        for (int kc = 0; kc < 2; kc++) {
            const ushort_t* qg = Q + base + (size_t)(s0 + 32 * w + 16 * nt + lm) * D_HEAD + kc * 32 + q * 8;
            uint4 u = *(const uint4*)qg;
            qf[nt][kc] = *(const short8*)&u;
        }

    // O^T accumulators: o[dj][nt]: lane holds O[s = s0+32w+16nt+lm][d = 16dj+4q+r]
    float4v o[4][2];
#pragma unroll
    for (int dj = 0; dj < 4; dj++)
#pragma unroll
        for (int nt = 0; nt < 2; nt++) o[dj][nt] = (float4v){0.f, 0.f, 0.f, 0.f};

    uint4 kr0, kr1, vr0, vr1;
    const ushort_t* kg0 = Kb + base + (size_t)srow * D_HEAD + sc;   // + tt*64*D_HEAD
    const ushort_t* vg0 = Vt + base + (size_t)srow * SEQ + sc;      // + tt*64

    // prologue: tile 0 regs -> LDS buf0 ; tile 1 -> regs
    kr0 = *(const uint4*)(kg0); kr1 = *(const uint4*)(kg0 + 8);
    vr0 = *(const uint4*)(vg0); vr1 = *(const uint4*)(vg0 + 8);
    *(uint4*)&Ks[0][srow][sc] = kr0; *(uint4*)&Ks[0][srow][sc + 8] = kr1;
    *(uint4*)&Vs[0][srow][sc] = vr0; *(uint4*)&Vs[0][srow][sc + 8] = vr1;
    kr0 = *(const uint4*)(kg0 + 64 * D_HEAD); kr1 = *(const uint4*)(kg0 + 64 * D_HEAD + 8);
    vr0 = *(const uint4*)(vg0 + 64);          vr1 = *(const uint4*)(vg0 + 64 + 8);
    __syncthreads();

    for (int tt = 0; tt < SEQ / 64; tt++) {
        int cur = tt & 1;
        // --- S^T = K Q^T : lane holds S[t = 64tt+16mt+4q+r][s = s0+32w+16nt+lm] ---
        float4v st[4][2];
#pragma unroll
        for (int mt = 0; mt < 4; mt++)
#pragma unroll
            for (int nt = 0; nt < 2; nt++) st[mt][nt] = (float4v){0.f, 0.f, 0.f, 0.f};
#pragma unroll
        for (int kc = 0; kc < 2; kc++) {
            short8 a[4];
#pragma unroll
            for (int mt = 0; mt < 4; mt++) a[mt] = *(const short8*)&Ks[cur][16 * mt + lm][kc * 32 + q * 8];
#pragma unroll
            for (int mt = 0; mt < 4; mt++)
#pragma unroll
                for (int nt = 0; nt < 2; nt++)
                    st[mt][nt] = __builtin_amdgcn_mfma_f32_16x16x32_bf16(a[mt], qf[nt][kc], st[mt][nt], 0, 0, 0);
        }
        // --- sigmoid -> packed bf16 P-fragments (registers only) ---
        short4v pf[4][2];
#pragma unroll
        for (int mt = 0; mt < 4; mt++)
#pragma unroll
            for (int nt = 0; nt < 2; nt++) {
                float4v s4 = st[mt][nt];
                union { unsigned int u[2]; short4v v; } pk;
                pk.u[0] = pack2bf(sigmoid_f(s4[0]), sigmoid_f(s4[1]));
                pk.u[1] = pack2bf(sigmoid_f(s4[2]), sigmoid_f(s4[3]));
                pf[mt][nt] = pk.v;
            }
        // --- O^T += V^T P : A = V^T-frag (m=d, k=t), B = P-frag (k=t, n=s) ---
#pragma unroll
        for (int mt = 0; mt < 4; mt++) {
            short4v vf[4];
#pragma unroll
            for (int dj = 0; dj < 4; dj++)
                vf[dj] = *(const short4v*)&Vs[cur][16 * dj + lm][16 * mt + 4 * q];
#pragma unroll
            for (int dj = 0; dj < 4; dj++)
#pragma unroll
                for (int nt = 0; nt < 2; nt++)
                    o[dj][nt] = __builtin_amdgcn_mfma_f32_16x16x16bf16_1k(vf[dj], pf[mt][nt], o[dj][nt], 0, 0, 0);
        }
        // --- pipeline: regs -> other buf; issue loads for tt+2 ---
        if (tt + 1 < SEQ / 64) {
            int nxt = 1 - cur;
            *(uint4*)&Ks[nxt][srow][sc] = kr0; *(uint4*)&Ks[nxt][srow][sc + 8] = kr1;
            *(uint4*)&Vs[nxt][srow][sc] = vr0; *(uint4*)&Vs[nxt][srow][sc + 8] = vr1;
            if (tt + 2 < SEQ / 64) {
                const ushort_t* kg = kg0 + (size_t)(tt + 2) * 64 * D_HEAD;
                const ushort_t* vg = vg0 + (tt + 2) * 64;
                kr0 = *(const uint4*)(kg); kr1 = *(const uint4*)(kg + 8);
                vr0 = *(const uint4*)(vg); vr1 = *(const uint4*)(vg + 8);
            }
        }
        __syncthreads();
    }

    // epilogue: Y = X + O  (float4: lane holds 4 consecutive d)
#pragma unroll
    for (int nt = 0; nt < 2; nt++) {
        int s = s0 + 32 * w + 16 * nt + lm;
        size_t rowoff = ((size_t)(b * SEQ + s)) * D_MODEL + h * D_HEAD;
        const float* xp = X + rowoff;
        float* yp = Y + rowoff;
#pragma unroll
        for (int dj = 0; dj < 4; dj++) {
            int d0 = 16 * dj + 4 * q;
            float4 xv = *(const float4*)(xp + d0);
            float4v ov = o[dj][nt];
            float4 r;
            r.x = xv.x + ov[0]; r.y = xv.y + ov[1];
            r.z = xv.z + ov[2]; r.w = xv.w + ov[3];
            *(float4*)(yp + d0) = r;
        }
    }
}

extern "C" void kernel_launch(void* const* d_in, const int* in_sizes, int n_in,
                              void* d_out, int out_size, void* d_ws, size_t ws_size,
                              hipStream_t stream) {
    const float* x   = (const float*)d_in[0];
    const float* Wq  = (const float*)d_in[1];
    const float* bq  = (const float*)d_in[2];
    const float* Wk  = (const float*)d_in[3];
    const float* bk  = (const float*)d_in[4];
    const float* Wv  = (const float*)d_in[5];
    const float* bv  = (const float*)d_in[6];
    const float* W1  = (const float*)d_in[7];
    const float* b1  = (const float*)d_in[8];
    const float* W2  = (const float*)d_in[9];
    const float* b2  = (const float*)d_in[10];
    const float* g1  = (const float*)d_in[11];
    const float* be1 = (const float*)d_in[12];
    const float* g2  = (const float*)d_in[13];
    const float* be2 = (const float*)d_in[14];
    float* out = (float*)d_out;

    char* p = (char*)d_ws;
    ushort_t* xn    = (ushort_t*)p; p += (size_t)NTOK * D_MODEL * 2;
    ushort_t* yn    = (ushort_t*)p; p += (size_t)NTOK * D_MODEL * 2;
    float*    y     = (float*)p;    p += (size_t)NTOK * D_MODEL * 4;
    ushort_t* qb    = (ushort_t*)p; p += (size_t)NTOK * D_MODEL * 2;
    ushort_t* kb    = (ushort_t*)p; p += (size_t)NTOK * D_MODEL * 2;
    ushort_t* vt    = (ushort_t*)p; p += (size_t)NTOK * D_MODEL * 2;
    ushort_t* hb    = (ushort_t*)p; p += (size_t)NTOK * D_FF * 2;
    ushort_t* Wqkvt = (ushort_t*)p; p += (size_t)3 * D_MODEL * D_MODEL * 2;
    ushort_t* W1t   = (ushort_t*)p; p += (size_t)D_MODEL * D_FF * 2;
    ushort_t* W2t   = (ushort_t*)p; p += (size_t)D_FF * D_MODEL * 2;

    // all weights -> bf16 transposed, single kernel (3*262144 + 2*1048576 elems)
    k_prep_weights<<<(3 * 262144 + 2 * 1048576 + 255) / 256, 256, 0, stream>>>(
        Wq, Wk, Wv, W1, W2, Wqkvt, W1t, W2t);

    // LN1
    k_layernorm<<<NTOK / 4, 256, 0, stream>>>(x, g1, be1, xn);

    // fused QKV projection (N=1536)
    dim3 gq(NTOK / 128, (3 * D_MODEL) / 128);
    k_gemm_qkv<<<gq, 256, 0, stream>>>(xn, Wqkvt, bq, bk, bv, qb, kb, vt);

    // attention + residual -> y
    dim3 ga(SEQ / 128, BATCH * N_HEADS);
    k_attention<<<ga, 256, 0, stream>>>(qb, kb, vt, x, y);

    // LN2
    k_layernorm<<<NTOK / 4, 256, 0, stream>>>(y, g2, be2, yn);

    // FFN
    dim3 g1d(NTOK / 128, D_FF / 128);
    k_gemm_ffn1<<<g1d, 256, 0, stream>>>(yn, W1t, b1, hb);
    dim3 g2d(NTOK / 128, D_MODEL / 128);
    k_gemm_ffn2<<<g2d, 256, 0, stream>>>(hb, W2t, b2, y, out);
}

// Round 4
// 262.955 us; speedup vs baseline: 1.4605x; 1.0451x over previous
//
#include <hip/hip_runtime.h>
#include <hip/hip_bf16.h>
#include <math.h>

#define D_MODEL 512
#define N_HEADS 8
#define D_HEAD 64
#define D_FF 2048
#define SEQ 2048
#define BATCH 4
#define NTOK (BATCH * SEQ)
#define QSCALE 0.04419417382415922f          // 1/sqrt(512)
#define QSCALE_L2E (-QSCALE * 1.44269504089f) // fold -log2(e)*scale into Q

typedef unsigned short ushort_t;
typedef __attribute__((ext_vector_type(8))) short short8;
typedef __attribute__((ext_vector_type(4))) float float4v;

static __device__ __forceinline__ ushort_t f2bf(float f) {
    union { float f; unsigned int i; } c; c.f = f;
    unsigned int i = c.i;
    unsigned int r = (i + 0x7FFFu + ((i >> 16) & 1u)) >> 16;   // RNE
    return (ushort_t)r;
}

static __device__ __forceinline__ unsigned int pack2bf(float a, float b) {
    union { __hip_bfloat162 h; unsigned int u; } c;
    c.h = __float22bfloat162_rn(make_float2(a, b));
    return c.u;
}

// sigmoid with scale pre-folded: input st = -s*scale*log2e  ->  1/(1+2^st)
static __device__ __forceinline__ float sig2(float x) {
    return __builtin_amdgcn_rcpf(1.0f + __builtin_amdgcn_exp2f(x));
}

// ------------- all weights -> bf16 transposed [N][K], one kernel -------------------------
__global__ __launch_bounds__(256) void k_prep_weights(const float* __restrict__ Wq,
                                                      const float* __restrict__ Wk,
                                                      const float* __restrict__ Wv,
                                                      const float* __restrict__ W1,
                                                      const float* __restrict__ W2,
                                                      ushort_t* __restrict__ Wqkvt,
                                                      ushort_t* __restrict__ W1t,
                                                      ushort_t* __restrict__ W2t) {
    int id = blockIdx.x * 256 + threadIdx.x;
    if (id < 3 * 262144) {
        int m = id >> 18, r = id & 262143;
        int k = r >> 9, n = r & 511;
        const float* src = (m == 0) ? Wq : ((m == 1) ? Wk : Wv);
        Wqkvt[((size_t)m * 512 + n) * 512 + k] = f2bf(src[r]);
        return;
    }
    int id2 = id - 3 * 262144;
    if (id2 < 1048576) {                 // W1 [512][2048] -> [2048][512]
        int k = id2 >> 11, n = id2 & 2047;
        W1t[(size_t)n * 512 + k] = f2bf(W1[id2]);
        return;
    }
    int id3 = id2 - 1048576;
    if (id3 < 1048576) {                 // W2 [2048][512] -> [512][2048]
        int k = id3 >> 9, n = id3 & 511;
        W2t[(size_t)n * 2048 + k] = f2bf(W2[id3]);
    }
}

// ---------------- layernorm: one wave per 512-wide row, out bf16 ----------------
__global__ __launch_bounds__(256) void k_layernorm(const float* __restrict__ X,
                                                   const float* __restrict__ g,
                                                   const float* __restrict__ be,
                                                   ushort_t* __restrict__ Out) {
    int row  = blockIdx.x * 4 + (threadIdx.x >> 6);
    int lane = threadIdx.x & 63;
    const float* x = X + (size_t)row * D_MODEL + lane * 8;
    float4 v0 = ((const float4*)x)[0];
    float4 v1 = ((const float4*)x)[1];
    float vals[8] = {v0.x, v0.y, v0.z, v0.w, v1.x, v1.y, v1.z, v1.w};
    float s = 0.f, sq = 0.f;
#pragma unroll
    for (int j = 0; j < 8; j++) { s += vals[j]; sq += vals[j] * vals[j]; }
#pragma unroll
    for (int off = 32; off; off >>= 1) { s += __shfl_xor(s, off); sq += __shfl_xor(sq, off); }
    float mu  = s * (1.0f / D_MODEL);
    float var = sq * (1.0f / D_MODEL) - mu * mu;
    float inv = rsqrtf(var + 1e-5f);
    const float* gp  = g  + lane * 8;
    const float* bp  = be + lane * 8;
    float4 g0 = ((const float4*)gp)[0], g1v = ((const float4*)gp)[1];
    float4 b0 = ((const float4*)bp)[0], b1v = ((const float4*)bp)[1];
    float gs[8] = {g0.x, g0.y, g0.z, g0.w, g1v.x, g1v.y, g1v.z, g1v.w};
    float bs[8] = {b0.x, b0.y, b0.z, b0.w, b1v.x, b1v.y, b1v.z, b1v.w};
    ushort_t o[8];
#pragma unroll
    for (int j = 0; j < 8; j++) o[j] = f2bf((vals[j] - mu) * inv * gs[j] + bs[j]);
    ushort_t* op = Out + (size_t)row * D_MODEL + lane * 8;
    *(uint4*)op = *(uint4*)o;
}

// ======== m97-style GEMM core: 128xBN tile, BK=32, global_load_lds double-buffer =========
// LDS layout UNPADDED row-major [rows][32] bf16 (64B rows) -- required by global_load_lds
// (wave-uniform base + lane*16). JW = 16-col frags per wave (4 -> BN=128, 2 -> BN=64).

static __device__ __forceinline__ void stage_tile(const ushort_t* __restrict__ G, int K,
                                                  ushort_t* L, int nchunks, int koff,
                                                  int w, int l) {
    // each 1KB chunk n: 16 rows x 32 cols; lane l covers row n*16+(l>>2), 16B piece (l&3)
#pragma unroll
    for (int n = w; n < nchunks; n += 4) {
        const ushort_t* g = G + (size_t)(n * 16 + (l >> 2)) * K + koff + (l & 3) * 8;
        __builtin_amdgcn_global_load_lds((const __attribute__((address_space(1))) void*)g,
                                         (__attribute__((address_space(3))) void*)(L + n * 512),
                                         16, 0, 0);
    }
}

template <int JW>
static __device__ __forceinline__ void gemm_core2(const ushort_t* __restrict__ A,
                                                  const ushort_t* __restrict__ Bt,
                                                  int K, int m0, int n0,
                                                  ushort_t* As, ushort_t* Bs,
                                                  float4v acc[4][JW]) {
    const int BBUF = JW * 1024;               // elements per B buffer
    int t = threadIdx.x, w = t >> 6, l = t & 63, q = l >> 4, lm = l & 15;
    int mb = (w & 1) * 64, nb = (w >> 1) * (JW * 16);
    const ushort_t* Ab = A + (size_t)m0 * K;
    const ushort_t* Bb = Bt + (size_t)n0 * K;
    int T = K >> 5;

    stage_tile(Ab, K, As, 8, 0, w, l);
    stage_tile(Bb, K, Bs, 2 * JW, 0, w, l);
    __syncthreads();

    for (int kt = 0; kt < T; kt++) {
        int cur = kt & 1;
        if (kt + 1 < T) {
            stage_tile(Ab, K, As + (1 - cur) * 4096, 8, (kt + 1) * 32, w, l);
            stage_tile(Bb, K, Bs + (1 - cur) * BBUF, 2 * JW, (kt + 1) * 32, w, l);
        }
        const ushort_t* asb = As + cur * 4096;
        const ushort_t* bsb = Bs + cur * BBUF;
        short8 a[4], b[JW];
#pragma unroll
        for (int i = 0; i < 4; i++) a[i] = *(const short8*)&asb[(mb + 16 * i + lm) * 32 + q * 8];
#pragma unroll
        for (int j = 0; j < JW; j++) b[j] = *(const short8*)&bsb[(nb + 16 * j + lm) * 32 + q * 8];
#pragma unroll
        for (int i = 0; i < 4; i++)
#pragma unroll
            for (int j = 0; j < JW; j++)
                acc[i][j] = __builtin_amdgcn_mfma_f32_16x16x32_bf16(a[i], b[j], acc[i][j], 0, 0, 0);
        __syncthreads();
    }
}

// ---------------- fused QKV projection (N=1536): q,k head-layout; v transposed ------------
__global__ __launch_bounds__(256) void k_gemm_qkv(const ushort_t* __restrict__ A,
                                                  const ushort_t* __restrict__ Bt,
                                                  const float* __restrict__ bq,
                                                  const float* __restrict__ bk,
                                                  const float* __restrict__ bv,
                                                  ushort_t* __restrict__ qb,
                                                  ushort_t* __restrict__ kb,
                                                  ushort_t* __restrict__ vt) {
    __shared__ __align__(16) ushort_t As[8192];
    __shared__ __align__(16) ushort_t Bs[8192];
    int m0 = blockIdx.x * 128, n0 = blockIdx.y * 128;
    float4v acc[4][4];
#pragma unroll
    for (int i = 0; i < 4; i++)
#pragma unroll
        for (int j = 0; j < 4; j++) acc[i][j] = (float4v){0.f, 0.f, 0.f, 0.f};
    gemm_core2<4>(A, Bt, D_MODEL, m0, n0, As, Bs, acc);

    int t = threadIdx.x, w = t >> 6, l = t & 63, q = l >> 4, lm = l & 15;
    int mb = (w & 1) * 64, nb = (w >> 1) * 64;
    int mat = n0 >> 9, c0 = n0 & 511;     // 128-blocks never cross the 512 boundaries
    const float* bias = (mat == 0) ? bq : ((mat == 1) ? bk : bv);
#pragma unroll
    for (int j = 0; j < 4; j++) {
        int cl = c0 + nb + 16 * j + lm;
        int hh = cl >> 6, dh = cl & 63;
        float bvv = bias[cl];
#pragma unroll
        for (int i = 0; i < 4; i++) {
            int mr0 = m0 + mb + 16 * i + q * 4;
            int bb = mr0 >> 11, ss0 = mr0 & (SEQ - 1);
            if (mat == 2) {
                union { ushort_t s[4]; uint2 v; } pk;
#pragma unroll
                for (int r = 0; r < 4; r++) pk.s[r] = f2bf(acc[i][j][r] + bvv);
                *(uint2*)&vt[((size_t)(bb * N_HEADS + hh) * D_HEAD + dh) * SEQ + ss0] = pk.v;
            } else {
                ushort_t* dst = (mat == 0) ? qb : kb;
                float sc = (mat == 0) ? QSCALE_L2E : 1.0f;
#pragma unroll
                for (int r = 0; r < 4; r++)
                    dst[((size_t)(bb * N_HEADS + hh) * SEQ + ss0 + r) * D_HEAD + dh] =
                        f2bf((acc[i][j][r] + bvv) * sc);
            }
        }
    }
}

// ---------------- FFN1: relu(yn @ W1 + b1) -> bf16 row-major ------------------------------
__global__ __launch_bounds__(256) void k_gemm_ffn1(const ushort_t* __restrict__ A,
                                                   const ushort_t* __restrict__ Bt,
                                                   const float* __restrict__ b1,
                                                   ushort_t* __restrict__ hb) {
    __shared__ __align__(16) ushort_t As[8192];
    __shared__ __align__(16) ushort_t Bs[8192];
    int m0 = blockIdx.x * 128, n0 = blockIdx.y * 128;
    float4v acc[4][4];
#pragma unroll
    for (int i = 0; i < 4; i++)
#pragma unroll
        for (int j = 0; j < 4; j++) acc[i][j] = (float4v){0.f, 0.f, 0.f, 0.f};
    gemm_core2<4>(A, Bt, D_MODEL, m0, n0, As, Bs, acc);

    int t = threadIdx.x, w = t >> 6, l = t & 63, q = l >> 4, lm = l & 15;
    int mb = (w & 1) * 64, nb = (w >> 1) * 64;
#pragma unroll
    for (int j = 0; j < 4; j++) {
        int cl = n0 + nb + 16 * j + lm;
        float bvv = b1[cl];
#pragma unroll
        for (int i = 0; i < 4; i++) {
            int mr0 = m0 + mb + 16 * i + q * 4;
#pragma unroll
            for (int r = 0; r < 4; r++)
                hb[(size_t)(mr0 + r) * D_FF + cl] = f2bf(fmaxf(acc[i][j][r] + bvv, 0.f));
        }
    }
}

// ---------------- FFN2: hb @ W2 + b2 + residual -> f32 out (128x64 tile) ------------------
__global__ __launch_bounds__(256) void k_gemm_ffn2(const ushort_t* __restrict__ A,
                                                   const ushort_t* __restrict__ Bt,
                                                   const float* __restrict__ b2,
                                                   const float* __restrict__ res,
                                                   float* __restrict__ out) {
    __shared__ __align__(16) ushort_t As[8192];
    __shared__ __align__(16) ushort_t Bs[4096];
    int m0 = blockIdx.x * 128, n0 = blockIdx.y * 64;
    float4v acc[4][2];
#pragma unroll
    for (int i = 0; i < 4; i++)
#pragma unroll
        for (int j = 0; j < 2; j++) acc[i][j] = (float4v){0.f, 0.f, 0.f, 0.f};
    gemm_core2<2>(A, Bt, D_FF, m0, n0, As, Bs, acc);

    int t = threadIdx.x, w = t >> 6, l = t & 63, q = l >> 4, lm = l & 15;
    int mb = (w & 1) * 64, nb = (w >> 1) * 32;
#pragma unroll
    for (int j = 0; j < 2; j++) {
        int cl = n0 + nb + 16 * j + lm;
        float bvv = b2[cl];
#pragma unroll
        for (int i = 0; i < 4; i++) {
            int mr0 = m0 + mb + 16 * i + q * 4;
#pragma unroll
            for (int r = 0; r < 4; r++) {
                size_t idx = (size_t)(mr0 + r) * D_MODEL + cl;
                out[idx] = acc[i][j][r] + bvv + res[idx];
            }
        }
    }
}

// ---------------- fused sigmoid attention: Y = X + sigmoid(QK^T/sqrt(D)) V ----------------
// Q,K: [BH][S][64] bf16 (Q pre-scaled by -scale*log2e); Vt: [BH][64][S] bf16; X,Y f32.
// S^T = K Q~^T -> sig2 -> Ps (b64 stores, wave-private rows) -> PV with K=32 MFMA.
__global__ __launch_bounds__(256) void k_attention(const ushort_t* __restrict__ Q,
                                                   const ushort_t* __restrict__ Kb,
                                                   const ushort_t* __restrict__ Vt,
                                                   const float* __restrict__ X,
                                                   float* __restrict__ Y) {
    __shared__ ushort_t Ks[2][64][72];
    __shared__ ushort_t Vs[2][64][72];
    __shared__ ushort_t Ps[128][72];
    int bh = blockIdx.y;
    int b = bh >> 3, h = bh & 7;
    size_t base = (size_t)bh * SEQ * D_HEAD;
    int s0 = blockIdx.x * 128;
    int t = threadIdx.x, w = t >> 6, l = t & 63, q = l >> 4, lm = l & 15;
    int srow = t >> 2, sc = (t & 3) * 16;

    // Q fragments in registers (reused for all 32 K/V tiles)
    short8 qf[2][2];
#pragma unroll
    for (int nt = 0; nt < 2; nt++)
#pragma unroll
        for (int kc = 0; kc < 2; kc++) {
            const ushort_t* qg = Q + base + (size_t)(s0 + 32 * w + 16 * nt + lm) * D_HEAD + kc * 32 + q * 8;
            uint4 u = *(const uint4*)qg;
            qf[nt][kc] = *(const short8*)&u;
        }

    float4v o[2][4];
#pragma unroll
    for (int nt = 0; nt < 2; nt++)
#pragma unroll
        for (int dj = 0; dj < 4; dj++) o[nt][dj] = (float4v){0.f, 0.f, 0.f, 0.f};

    uint4 kr0, kr1, vr0, vr1;
    const ushort_t* kg0 = Kb + base + (size_t)srow * D_HEAD + sc;
    const ushort_t* vg0 = Vt + base + (size_t)srow * SEQ + sc;

    kr0 = *(const uint4*)(kg0); kr1 = *(const uint4*)(kg0 + 8);
    vr0 = *(const uint4*)(vg0); vr1 = *(const uint4*)(vg0 + 8);
    *(uint4*)&Ks[0][srow][sc] = kr0; *(uint4*)&Ks[0][srow][sc + 8] = kr1;
    *(uint4*)&Vs[0][srow][sc] = vr0; *(uint4*)&Vs[0][srow][sc + 8] = vr1;
    kr0 = *(const uint4*)(kg0 + 64 * D_HEAD); kr1 = *(const uint4*)(kg0 + 64 * D_HEAD + 8);
    vr0 = *(const uint4*)(vg0 + 64);          vr1 = *(const uint4*)(vg0 + 64 + 8);
    __syncthreads();

    for (int tt = 0; tt < SEQ / 64; tt++) {
        int cur = tt & 1;
        // --- S^T = K Q~^T : lane holds S~[t = 64tt+16mt+4q+r][s = s0+32w+16nt+lm] ---
        float4v st[4][2];
#pragma unroll
        for (int mt = 0; mt < 4; mt++)
#pragma unroll
            for (int nt = 0; nt < 2; nt++) st[mt][nt] = (float4v){0.f, 0.f, 0.f, 0.f};
#pragma unroll
        for (int kc = 0; kc < 2; kc++) {
            short8 a[4];
#pragma unroll
            for (int mt = 0; mt < 4; mt++) a[mt] = *(const short8*)&Ks[cur][16 * mt + lm][kc * 32 + q * 8];
#pragma unroll
            for (int mt = 0; mt < 4; mt++)
#pragma unroll
                for (int nt = 0; nt < 2; nt++)
                    st[mt][nt] = __builtin_amdgcn_mfma_f32_16x16x32_bf16(a[mt], qf[nt][kc], st[mt][nt], 0, 0, 0);
        }
        // --- sigmoid + P store (b64, contiguous t; wave-private rows) ---
#pragma unroll
        for (int mt = 0; mt < 4; mt++)
#pragma unroll
            for (int nt = 0; nt < 2; nt++) {
                float4v s4 = st[mt][nt];
                uint2 pk;
                pk.x = pack2bf(sig2(s4[0]), sig2(s4[1]));
                pk.y = pack2bf(sig2(s4[2]), sig2(s4[3]));
                *(uint2*)&Ps[32 * w + 16 * nt + lm][16 * mt + 4 * q] = pk;
            }
        // --- O += P V  (A=P rows s, B=Vs rows d), K=32 full-rate MFMA ---
#pragma unroll
        for (int kc = 0; kc < 2; kc++) {
            short8 ap[2], bv[4];
#pragma unroll
            for (int nt = 0; nt < 2; nt++) ap[nt] = *(const short8*)&Ps[32 * w + 16 * nt + lm][kc * 32 + q * 8];
#pragma unroll
            for (int dj = 0; dj < 4; dj++) bv[dj] = *(const short8*)&Vs[cur][16 * dj + lm][kc * 32 + q * 8];
#pragma unroll
            for (int nt = 0; nt < 2; nt++)
#pragma unroll
                for (int dj = 0; dj < 4; dj++)
                    o[nt][dj] = __builtin_amdgcn_mfma_f32_16x16x32_bf16(ap[nt], bv[dj], o[nt][dj], 0, 0, 0);
        }
        // --- pipeline: regs -> other buf; issue loads for tt+2 ---
        if (tt + 1 < SEQ / 64) {
            int nxt = 1 - cur;
            *(uint4*)&Ks[nxt][srow][sc] = kr0; *(uint4*)&Ks[nxt][srow][sc + 8] = kr1;
            *(uint4*)&Vs[nxt][srow][sc] = vr0; *(uint4*)&Vs[nxt][srow][sc + 8] = vr1;
            if (tt + 2 < SEQ / 64) {
                const ushort_t* kg = kg0 + (size_t)(tt + 2) * 64 * D_HEAD;
                const ushort_t* vg = vg0 + (tt + 2) * 64;
                kr0 = *(const uint4*)(kg); kr1 = *(const uint4*)(kg + 8);
                vr0 = *(const uint4*)(vg); vr1 = *(const uint4*)(vg + 8);
            }
        }
        __syncthreads();
    }

    // epilogue: Y = X + O  (lanes lm cover 16 consecutive d -> coalesced)
#pragma unroll
    for (int nt = 0; nt < 2; nt++)
#pragma unroll
        for (int dj = 0; dj < 4; dj++) {
            int d = 16 * dj + lm;
#pragma unroll
            for (int r = 0; r < 4; r++) {
                int s = s0 + 32 * w + 16 * nt + q * 4 + r;
                size_t idx = ((size_t)(b * SEQ + s)) * D_MODEL + h * D_HEAD + d;
                Y[idx] = X[idx] + o[nt][dj][r];
            }
        }
}

extern "C" void kernel_launch(void* const* d_in, const int* in_sizes, int n_in,
                              void* d_out, int out_size, void* d_ws, size_t ws_size,
                              hipStream_t stream) {
    const float* x   = (const float*)d_in[0];
    const float* Wq  = (const float*)d_in[1];
    const float* bq  = (const float*)d_in[2];
    const float* Wk  = (const float*)d_in[3];
    const float* bk  = (const float*)d_in[4];
    const float* Wv  = (const float*)d_in[5];
    const float* bv  = (const float*)d_in[6];
    const float* W1  = (const float*)d_in[7];
    const float* b1  = (const float*)d_in[8];
    const float* W2  = (const float*)d_in[9];
    const float* b2  = (const float*)d_in[10];
    const float* g1  = (const float*)d_in[11];
    const float* be1 = (const float*)d_in[12];
    const float* g2  = (const float*)d_in[13];
    const float* be2 = (const float*)d_in[14];
    float* out = (float*)d_out;

    char* p = (char*)d_ws;
    ushort_t* xn    = (ushort_t*)p; p += (size_t)NTOK * D_MODEL * 2;
    ushort_t* yn    = (ushort_t*)p; p += (size_t)NTOK * D_MODEL * 2;
    float*    y     = (float*)p;    p += (size_t)NTOK * D_MODEL * 4;
    ushort_t* qb    = (ushort_t*)p; p += (size_t)NTOK * D_MODEL * 2;
    ushort_t* kb    = (ushort_t*)p; p += (size_t)NTOK * D_MODEL * 2;
    ushort_t* vt    = (ushort_t*)p; p += (size_t)NTOK * D_MODEL * 2;
    ushort_t* hb    = (ushort_t*)p; p += (size_t)NTOK * D_FF * 2;
    ushort_t* Wqkvt = (ushort_t*)p; p += (size_t)3 * D_MODEL * D_MODEL * 2;
    ushort_t* W1t   = (ushort_t*)p; p += (size_t)D_MODEL * D_FF * 2;
    ushort_t* W2t   = (ushort_t*)p; p += (size_t)D_FF * D_MODEL * 2;

    k_prep_weights<<<(3 * 262144 + 2 * 1048576 + 255) / 256, 256, 0, stream>>>(
        Wq, Wk, Wv, W1, W2, Wqkvt, W1t, W2t);

    k_layernorm<<<NTOK / 4, 256, 0, stream>>>(x, g1, be1, xn);

    dim3 gq(NTOK / 128, (3 * D_MODEL) / 128);
    k_gemm_qkv<<<gq, 256, 0, stream>>>(xn, Wqkvt, bq, bk, bv, qb, kb, vt);

    dim3 ga(SEQ / 128, BATCH * N_HEADS);
    k_attention<<<ga, 256, 0, stream>>>(qb, kb, vt, x, y);

    k_layernorm<<<NTOK / 4, 256, 0, stream>>>(y, g2, be2, yn);

    dim3 g1d(NTOK / 128, D_FF / 128);
    k_gemm_ffn1<<<g1d, 256, 0, stream>>>(yn, W1t, b1, hb);
    dim3 g2d(NTOK / 128, D_MODEL / 64);
    k_gemm_ffn2<<<g2d, 256, 0, stream>>>(hb, W2t, b2, y, out);
}

// Round 5
// 256.982 us; speedup vs baseline: 1.4945x; 1.0232x over previous
//
#include <hip/hip_runtime.h>
#include <hip/hip_bf16.h>
#include <math.h>

#define D_MODEL 512
#define N_HEADS 8
#define D_HEAD 64
#define D_FF 2048
#define SEQ 2048
#define BATCH 4
#define NTOK (BATCH * SEQ)
#define QSCALE 0.04419417382415922f          // 1/sqrt(512)
#define QSCALE_L2E (-QSCALE * 1.44269504089f) // fold -log2(e)*scale into Q

typedef unsigned short ushort_t;
typedef __attribute__((ext_vector_type(8))) short short8;
typedef __attribute__((ext_vector_type(4))) float float4v;

static __device__ __forceinline__ ushort_t f2bf(float f) {
    union { float f; unsigned int i; } c; c.f = f;
    unsigned int i = c.i;
    unsigned int r = (i + 0x7FFFu + ((i >> 16) & 1u)) >> 16;   // RNE
    return (ushort_t)r;
}

static __device__ __forceinline__ unsigned int pack2bf(float a, float b) {
    union { __hip_bfloat162 h; unsigned int u; } c;
    c.h = __float22bfloat162_rn(make_float2(a, b));
    return c.u;
}

// sigmoid with scale pre-folded: input st = -s*scale*log2e  ->  1/(1+2^st)
static __device__ __forceinline__ float sig2(float x) {
    return __builtin_amdgcn_rcpf(1.0f + __builtin_amdgcn_exp2f(x));
}

// ------------- all weights -> bf16 transposed [N][K], one kernel -------------------------
__global__ __launch_bounds__(256) void k_prep_weights(const float* __restrict__ Wq,
                                                      const float* __restrict__ Wk,
                                                      const float* __restrict__ Wv,
                                                      const float* __restrict__ W1,
                                                      const float* __restrict__ W2,
                                                      ushort_t* __restrict__ Wqkvt,
                                                      ushort_t* __restrict__ W1t,
                                                      ushort_t* __restrict__ W2t) {
    int id = blockIdx.x * 256 + threadIdx.x;
    if (id < 3 * 262144) {
        int m = id >> 18, r = id & 262143;
        int k = r >> 9, n = r & 511;
        const float* src = (m == 0) ? Wq : ((m == 1) ? Wk : Wv);
        Wqkvt[((size_t)m * 512 + n) * 512 + k] = f2bf(src[r]);
        return;
    }
    int id2 = id - 3 * 262144;
    if (id2 < 1048576) {                 // W1 [512][2048] -> [2048][512]
        int k = id2 >> 11, n = id2 & 2047;
        W1t[(size_t)n * 512 + k] = f2bf(W1[id2]);
        return;
    }
    int id3 = id2 - 1048576;
    if (id3 < 1048576) {                 // W2 [2048][512] -> [512][2048]
        int k = id3 >> 9, n = id3 & 511;
        W2t[(size_t)n * 2048 + k] = f2bf(W2[id3]);
    }
}

// ---------------- layernorm: one wave per 512-wide row, out bf16 ----------------
__global__ __launch_bounds__(256) void k_layernorm(const float* __restrict__ X,
                                                   const float* __restrict__ g,
                                                   const float* __restrict__ be,
                                                   ushort_t* __restrict__ Out) {
    int row  = blockIdx.x * 4 + (threadIdx.x >> 6);
    int lane = threadIdx.x & 63;
    const float* x = X + (size_t)row * D_MODEL + lane * 8;
    float4 v0 = ((const float4*)x)[0];
    float4 v1 = ((const float4*)x)[1];
    float vals[8] = {v0.x, v0.y, v0.z, v0.w, v1.x, v1.y, v1.z, v1.w};
    float s = 0.f, sq = 0.f;
#pragma unroll
    for (int j = 0; j < 8; j++) { s += vals[j]; sq += vals[j] * vals[j]; }
#pragma unroll
    for (int off = 32; off; off >>= 1) { s += __shfl_xor(s, off); sq += __shfl_xor(sq, off); }
    float mu  = s * (1.0f / D_MODEL);
    float var = sq * (1.0f / D_MODEL) - mu * mu;
    float inv = rsqrtf(var + 1e-5f);
    const float* gp  = g  + lane * 8;
    const float* bp  = be + lane * 8;
    float4 g0 = ((const float4*)gp)[0], g1v = ((const float4*)gp)[1];
    float4 b0 = ((const float4*)bp)[0], b1v = ((const float4*)bp)[1];
    float gs[8] = {g0.x, g0.y, g0.z, g0.w, g1v.x, g1v.y, g1v.z, g1v.w};
    float bs[8] = {b0.x, b0.y, b0.z, b0.w, b1v.x, b1v.y, b1v.z, b1v.w};
    ushort_t o[8];
#pragma unroll
    for (int j = 0; j < 8; j++) o[j] = f2bf((vals[j] - mu) * inv * gs[j] + bs[j]);
    ushort_t* op = Out + (size_t)row * D_MODEL + lane * 8;
    *(uint4*)op = *(uint4*)o;
}

// ======== m97-style GEMM core: 128xBN tile, BK=32, global_load_lds double-buffer =========
static __device__ __forceinline__ void stage_tile(const ushort_t* __restrict__ G, int K,
                                                  ushort_t* L, int nchunks, int koff,
                                                  int w, int l) {
#pragma unroll
    for (int n = w; n < nchunks; n += 4) {
        const ushort_t* g = G + (size_t)(n * 16 + (l >> 2)) * K + koff + (l & 3) * 8;
        __builtin_amdgcn_global_load_lds((const __attribute__((address_space(1))) void*)g,
                                         (__attribute__((address_space(3))) void*)(L + n * 512),
                                         16, 0, 0);
    }
}

template <int JW>
static __device__ __forceinline__ void gemm_core2(const ushort_t* __restrict__ A,
                                                  const ushort_t* __restrict__ Bt,
                                                  int K, int m0, int n0,
                                                  ushort_t* As, ushort_t* Bs,
                                                  float4v acc[4][JW]) {
    const int BBUF = JW * 1024;
    int t = threadIdx.x, w = t >> 6, l = t & 63, q = l >> 4, lm = l & 15;
    int mb = (w & 1) * 64, nb = (w >> 1) * (JW * 16);
    const ushort_t* Ab = A + (size_t)m0 * K;
    const ushort_t* Bb = Bt + (size_t)n0 * K;
    int T = K >> 5;

    stage_tile(Ab, K, As, 8, 0, w, l);
    stage_tile(Bb, K, Bs, 2 * JW, 0, w, l);
    __syncthreads();

    for (int kt = 0; kt < T; kt++) {
        int cur = kt & 1;
        if (kt + 1 < T) {
            stage_tile(Ab, K, As + (1 - cur) * 4096, 8, (kt + 1) * 32, w, l);
            stage_tile(Bb, K, Bs + (1 - cur) * BBUF, 2 * JW, (kt + 1) * 32, w, l);
        }
        const ushort_t* asb = As + cur * 4096;
        const ushort_t* bsb = Bs + cur * BBUF;
        short8 a[4], b[JW];
#pragma unroll
        for (int i = 0; i < 4; i++) a[i] = *(const short8*)&asb[(mb + 16 * i + lm) * 32 + q * 8];
#pragma unroll
        for (int j = 0; j < JW; j++) b[j] = *(const short8*)&bsb[(nb + 16 * j + lm) * 32 + q * 8];
#pragma unroll
        for (int i = 0; i < 4; i++)
#pragma unroll
            for (int j = 0; j < JW; j++)
                acc[i][j] = __builtin_amdgcn_mfma_f32_16x16x32_bf16(a[i], b[j], acc[i][j], 0, 0, 0);
        __syncthreads();
    }
}

// ---------------- fused QKV projection (N=1536): q,k head-layout; v transposed ------------
__global__ __launch_bounds__(256) void k_gemm_qkv(const ushort_t* __restrict__ A,
                                                  const ushort_t* __restrict__ Bt,
                                                  const float* __restrict__ bq,
                                                  const float* __restrict__ bk,
                                                  const float* __restrict__ bv,
                                                  ushort_t* __restrict__ qb,
                                                  ushort_t* __restrict__ kb,
                                                  ushort_t* __restrict__ vt) {
    __shared__ __align__(16) ushort_t As[8192];
    __shared__ __align__(16) ushort_t Bs[8192];
    int m0 = blockIdx.x * 128, n0 = blockIdx.y * 128;
    float4v acc[4][4];
#pragma unroll
    for (int i = 0; i < 4; i++)
#pragma unroll
        for (int j = 0; j < 4; j++) acc[i][j] = (float4v){0.f, 0.f, 0.f, 0.f};
    gemm_core2<4>(A, Bt, D_MODEL, m0, n0, As, Bs, acc);

    int t = threadIdx.x, w = t >> 6, l = t & 63, q = l >> 4, lm = l & 15;
    int mb = (w & 1) * 64, nb = (w >> 1) * 64;
    int mat = n0 >> 9, c0 = n0 & 511;
    const float* bias = (mat == 0) ? bq : ((mat == 1) ? bk : bv);
#pragma unroll
    for (int j = 0; j < 4; j++) {
        int cl = c0 + nb + 16 * j + lm;
        int hh = cl >> 6, dh = cl & 63;
        float bvv = bias[cl];
#pragma unroll
        for (int i = 0; i < 4; i++) {
            int mr0 = m0 + mb + 16 * i + q * 4;
            int bb = mr0 >> 11, ss0 = mr0 & (SEQ - 1);
            if (mat == 2) {
                union { ushort_t s[4]; uint2 v; } pk;
#pragma unroll
                for (int r = 0; r < 4; r++) pk.s[r] = f2bf(acc[i][j][r] + bvv);
                *(uint2*)&vt[((size_t)(bb * N_HEADS + hh) * D_HEAD + dh) * SEQ + ss0] = pk.v;
            } else {
                ushort_t* dst = (mat == 0) ? qb : kb;
                float sc = (mat == 0) ? QSCALE_L2E : 1.0f;
#pragma unroll
                for (int r = 0; r < 4; r++)
                    dst[((size_t)(bb * N_HEADS + hh) * SEQ + ss0 + r) * D_HEAD + dh] =
                        f2bf((acc[i][j][r] + bvv) * sc);
            }
        }
    }
}

// ---------------- FFN1: relu(yn @ W1 + b1) -> bf16 row-major ------------------------------
__global__ __launch_bounds__(256) void k_gemm_ffn1(const ushort_t* __restrict__ A,
                                                   const ushort_t* __restrict__ Bt,
                                                   const float* __restrict__ b1,
                                                   ushort_t* __restrict__ hb) {
    __shared__ __align__(16) ushort_t As[8192];
    __shared__ __align__(16) ushort_t Bs[8192];
    int m0 = blockIdx.x * 128, n0 = blockIdx.y * 128;
    float4v acc[4][4];
#pragma unroll
    for (int i = 0; i < 4; i++)
#pragma unroll
        for (int j = 0; j < 4; j++) acc[i][j] = (float4v){0.f, 0.f, 0.f, 0.f};
    gemm_core2<4>(A, Bt, D_MODEL, m0, n0, As, Bs, acc);

    int t = threadIdx.x, w = t >> 6, l = t & 63, q = l >> 4, lm = l & 15;
    int mb = (w & 1) * 64, nb = (w >> 1) * 64;
#pragma unroll
    for (int j = 0; j < 4; j++) {
        int cl = n0 + nb + 16 * j + lm;
        float bvv = b1[cl];
#pragma unroll
        for (int i = 0; i < 4; i++) {
            int mr0 = m0 + mb + 16 * i + q * 4;
#pragma unroll
            for (int r = 0; r < 4; r++)
                hb[(size_t)(mr0 + r) * D_FF + cl] = f2bf(fmaxf(acc[i][j][r] + bvv, 0.f));
        }
    }
}

// ---------------- FFN2: hb @ W2 + b2 + residual -> f32 out (128x64 tile) ------------------
__global__ __launch_bounds__(256) void k_gemm_ffn2(const ushort_t* __restrict__ A,
                                                   const ushort_t* __restrict__ Bt,
                                                   const float* __restrict__ b2,
                                                   const float* __restrict__ res,
                                                   float* __restrict__ out) {
    __shared__ __align__(16) ushort_t As[8192];
    __shared__ __align__(16) ushort_t Bs[4096];
    int m0 = blockIdx.x * 128, n0 = blockIdx.y * 64;
    float4v acc[4][2];
#pragma unroll
    for (int i = 0; i < 4; i++)
#pragma unroll
        for (int j = 0; j < 2; j++) acc[i][j] = (float4v){0.f, 0.f, 0.f, 0.f};
    gemm_core2<2>(A, Bt, D_FF, m0, n0, As, Bs, acc);

    int t = threadIdx.x, w = t >> 6, l = t & 63, q = l >> 4, lm = l & 15;
    int mb = (w & 1) * 64, nb = (w >> 1) * 32;
#pragma unroll
    for (int j = 0; j < 2; j++) {
        int cl = n0 + nb + 16 * j + lm;
        float bvv = b2[cl];
#pragma unroll
        for (int i = 0; i < 4; i++) {
            int mr0 = m0 + mb + 16 * i + q * 4;
#pragma unroll
            for (int r = 0; r < 4; r++) {
                size_t idx = (size_t)(mr0 + r) * D_MODEL + cl;
                out[idx] = acc[i][j][r] + bvv + res[idx];
            }
        }
    }
}

// ---------------- fused sigmoid attention: Y = X + sigmoid(QK^T/sqrt(D)) V ----------------
// 512 threads / 8 waves per block; wave w owns 16 Q-rows (s0+16w+lm). Grid 512 blocks
// (2/CU) x 8 waves -> 16 waves/CU (50% cap) vs 8 before: occupancy was grid-capped.
__global__ __launch_bounds__(512) void k_attention(const ushort_t* __restrict__ Q,
                                                   const ushort_t* __restrict__ Kb,
                                                   const ushort_t* __restrict__ Vt,
                                                   const float* __restrict__ X,
                                                   float* __restrict__ Y) {
    __shared__ ushort_t Ks[2][64][72];
    __shared__ ushort_t Vs[2][64][72];
    __shared__ ushort_t Ps[128][72];
    int bh = blockIdx.y;
    int b = bh >> 3, h = bh & 7;
    size_t base = (size_t)bh * SEQ * D_HEAD;
    int s0 = blockIdx.x * 128;
    int t = threadIdx.x, w = t >> 6, l = t & 63, q = l >> 4, lm = l & 15;
    int srow = t >> 3, sc = (t & 7) * 8;          // 512 thr x 16B cover 64x64 bf16 tile

    // Q fragments in registers (reused for all 32 K/V tiles); wave w rows s0+16w+lm
    short8 qf[2];
#pragma unroll
    for (int kc = 0; kc < 2; kc++) {
        const ushort_t* qg = Q + base + (size_t)(s0 + 16 * w + lm) * D_HEAD + kc * 32 + q * 8;
        uint4 u = *(const uint4*)qg;
        qf[kc] = *(const short8*)&u;
    }

    float4v o[4];
#pragma unroll
    for (int dj = 0; dj < 4; dj++) o[dj] = (float4v){0.f, 0.f, 0.f, 0.f};

    uint4 kr, vr;
    const ushort_t* kg0 = Kb + base + (size_t)srow * D_HEAD + sc;
    const ushort_t* vg0 = Vt + base + (size_t)srow * SEQ + sc;

    kr = *(const uint4*)(kg0); vr = *(const uint4*)(vg0);
    *(uint4*)&Ks[0][srow][sc] = kr; *(uint4*)&Vs[0][srow][sc] = vr;
    kr = *(const uint4*)(kg0 + 64 * D_HEAD); vr = *(const uint4*)(vg0 + 64);
    __syncthreads();

    for (int tt = 0; tt < SEQ / 64; tt++) {
        int cur = tt & 1;
        // --- S^T = K Q~^T : lane holds S~[t = 64tt+16mt+4q+r][s = s0+16w+lm] ---
        float4v st[4];
#pragma unroll
        for (int mt = 0; mt < 4; mt++) st[mt] = (float4v){0.f, 0.f, 0.f, 0.f};
#pragma unroll
        for (int kc = 0; kc < 2; kc++) {
#pragma unroll
            for (int mt = 0; mt < 4; mt++) {
                short8 a = *(const short8*)&Ks[cur][16 * mt + lm][kc * 32 + q * 8];
                st[mt] = __builtin_amdgcn_mfma_f32_16x16x32_bf16(a, qf[kc], st[mt], 0, 0, 0);
            }
        }
        // --- sigmoid + P store (b64, contiguous t; wave-private rows) ---
#pragma unroll
        for (int mt = 0; mt < 4; mt++) {
            float4v s4 = st[mt];
            uint2 pk;
            pk.x = pack2bf(sig2(s4[0]), sig2(s4[1]));
            pk.y = pack2bf(sig2(s4[2]), sig2(s4[3]));
            *(uint2*)&Ps[16 * w + lm][16 * mt + 4 * q] = pk;
        }
        // --- O += P V  (A=P rows s, B=Vs rows d), K=32 full-rate MFMA ---
#pragma unroll
        for (int kc = 0; kc < 2; kc++) {
            short8 ap = *(const short8*)&Ps[16 * w + lm][kc * 32 + q * 8];
#pragma unroll
            for (int dj = 0; dj < 4; dj++) {
                short8 bv = *(const short8*)&Vs[cur][16 * dj + lm][kc * 32 + q * 8];
                o[dj] = __builtin_amdgcn_mfma_f32_16x16x32_bf16(ap, bv, o[dj], 0, 0, 0);
            }
        }
        // --- pipeline: regs -> other buf; issue loads for tt+2 ---
        if (tt + 1 < SEQ / 64) {
            int nxt = 1 - cur;
            *(uint4*)&Ks[nxt][srow][sc] = kr; *(uint4*)&Vs[nxt][srow][sc] = vr;
            if (tt + 2 < SEQ / 64) {
                kr = *(const uint4*)(kg0 + (size_t)(tt + 2) * 64 * D_HEAD);
                vr = *(const uint4*)(vg0 + (tt + 2) * 64);
            }
        }
        __syncthreads();
    }

    // epilogue: Y = X + O  (lanes lm cover 16 consecutive d -> coalesced)
#pragma unroll
    for (int dj = 0; dj < 4; dj++) {
        int d = 16 * dj + lm;
#pragma unroll
        for (int r = 0; r < 4; r++) {
            int s = s0 + 16 * w + q * 4 + r;
            size_t idx = ((size_t)(b * SEQ + s)) * D_MODEL + h * D_HEAD + d;
            Y[idx] = X[idx] + o[dj][r];
        }
    }
}

extern "C" void kernel_launch(void* const* d_in, const int* in_sizes, int n_in,
                              void* d_out, int out_size, void* d_ws, size_t ws_size,
                              hipStream_t stream) {
    const float* x   = (const float*)d_in[0];
    const float* Wq  = (const float*)d_in[1];
    const float* bq  = (const float*)d_in[2];
    const float* Wk  = (const float*)d_in[3];
    const float* bk  = (const float*)d_in[4];
    const float* Wv  = (const float*)d_in[5];
    const float* bv  = (const float*)d_in[6];
    const float* W1  = (const float*)d_in[7];
    const float* b1  = (const float*)d_in[8];
    const float* W2  = (const float*)d_in[9];
    const float* b2  = (const float*)d_in[10];
    const float* g1  = (const float*)d_in[11];
    const float* be1 = (const float*)d_in[12];
    const float* g2  = (const float*)d_in[13];
    const float* be2 = (const float*)d_in[14];
    float* out = (float*)d_out;

    char* p = (char*)d_ws;
    ushort_t* xn    = (ushort_t*)p; p += (size_t)NTOK * D_MODEL * 2;
    ushort_t* yn    = (ushort_t*)p; p += (size_t)NTOK * D_MODEL * 2;
    float*    y     = (float*)p;    p += (size_t)NTOK * D_MODEL * 4;
    ushort_t* qb    = (ushort_t*)p; p += (size_t)NTOK * D_MODEL * 2;
    ushort_t* kb    = (ushort_t*)p; p += (size_t)NTOK * D_MODEL * 2;
    ushort_t* vt    = (ushort_t*)p; p += (size_t)NTOK * D_MODEL * 2;
    ushort_t* hb    = (ushort_t*)p; p += (size_t)NTOK * D_FF * 2;
    ushort_t* Wqkvt = (ushort_t*)p; p += (size_t)3 * D_MODEL * D_MODEL * 2;
    ushort_t* W1t   = (ushort_t*)p; p += (size_t)D_MODEL * D_FF * 2;
    ushort_t* W2t   = (ushort_t*)p; p += (size_t)D_FF * D_MODEL * 2;

    k_prep_weights<<<(3 * 262144 + 2 * 1048576 + 255) / 256, 256, 0, stream>>>(
        Wq, Wk, Wv, W1, W2, Wqkvt, W1t, W2t);

    k_layernorm<<<NTOK / 4, 256, 0, stream>>>(x, g1, be1, xn);

    dim3 gq(NTOK / 128, (3 * D_MODEL) / 128);
    k_gemm_qkv<<<gq, 256, 0, stream>>>(xn, Wqkvt, bq, bk, bv, qb, kb, vt);

    dim3 ga(SEQ / 128, BATCH * N_HEADS);
    k_attention<<<ga, 512, 0, stream>>>(qb, kb, vt, x, y);

    k_layernorm<<<NTOK / 4, 256, 0, stream>>>(y, g2, be2, yn);

    dim3 g1d(NTOK / 128, D_FF / 128);
    k_gemm_ffn1<<<g1d, 256, 0, stream>>>(yn, W1t, b1, hb);
    dim3 g2d(NTOK / 128, D_MODEL / 64);
    k_gemm_ffn2<<<g2d, 256, 0, stream>>>(hb, W2t, b2, y, out);
}